// Round 2
// baseline (2711.162 us; speedup 1.0000x reference)
//
#include <hip/hip_runtime.h>

#define D     200
#define H     4
#define DH    50
#define NE    38
#define NTY   4
#define NC    608      // edge combos = 38*4*4
#define NCT   612      // + 4 self combos
#define BG    256      // graphs
#define LG    1024     // edges per graph
#define EE    262144   // E
#define NN    51200    // N
#define EA    313344   // E + N

// ---------------- histogram / combo / degrees ----------------
__global__ __launch_bounds__(256) void k_hist(const int* __restrict__ ei, const int* __restrict__ et,
                                              const int* __restrict__ nt, int* hist, int* outdeg, int* indeg,
                                              unsigned short* __restrict__ combo) {
    int e = blockIdx.x * 256 + threadIdx.x;
    if (e >= EE) return;
    int s = ei[e], d = ei[EE + e];
    int c = et[e] * 16 + nt[s] * 4 + nt[d];
    combo[e] = (unsigned short)c;
    atomicAdd(&hist[c], 1);
    atomicAdd(&outdeg[s], 1);
    atomicAdd(&indeg[d], 1);
}

__global__ __launch_bounds__(256) void k_ntcnt(const int* __restrict__ nt, int* ntcnt) {
    int n = blockIdx.x * 256 + threadIdx.x;
    if (n < NN) atomicAdd(&ntcnt[nt[n]], 1);
}

__global__ void k_tcnt(const int* __restrict__ hist, int* tcnt) {
    int t = threadIdx.x;
    if (t < NE) { int s = 0; for (int i = 0; i < 16; i++) s += hist[t*16 + i]; tcnt[t] = s; }
}

// ---------------- per-(node,type) signed coefficients ----------------
__global__ __launch_bounds__(256) void k_coef(const int* __restrict__ ei, const int* __restrict__ et,
                                              float* coef) {
    int e = blockIdx.x * 256 + threadIdx.x;
    if (e >= EE) return;
    int s = ei[e], d = ei[EE + e], t = et[e];
    unsafeAtomicAdd(&coef[(size_t)d * NE + t],  1.f);
    unsafeAtomicAdd(&coef[(size_t)s * NE + t], -1.f);
}

// sums[t][:] = sum_n coef[n][t] * x[n][:]  -- x read once, coalesced
__global__ __launch_bounds__(256) void k_xfsum2(const float* __restrict__ x, const float* __restrict__ coef,
                                                float* sums) {
    __shared__ float acc[NE * D];
    for (int i = threadIdx.x; i < NE * D; i += 256) acc[i] = 0.f;
    __syncthreads();
    int wave = threadIdx.x >> 6, lane = threadIdx.x & 63;
    int nw = gridDim.x * 4;
    for (int n = blockIdx.x * 4 + wave; n < NN; n += nw) {
        float xv[4];
        #pragma unroll
        for (int j = 0; j < 4; j++) { int dd = lane + 64*j; xv[j] = (dd < D) ? x[(size_t)n*D + dd] : 0.f; }
        for (int t = 0; t < NE; t++) {
            float c = coef[(size_t)n * NE + t];
            if (c != 0.f) {
                #pragma unroll
                for (int j = 0; j < 4; j++) { int dd = lane + 64*j; if (dd < D) atomicAdd(&acc[t*D + dd], c * xv[j]); }
            }
        }
    }
    __syncthreads();
    for (int i = threadIdx.x; i < NE * D; i += 256) {
        float v = acc[i];
        if (v != 0.f) unsafeAtomicAdd(&sums[i], v);
    }
}

// ---------------- CSR build: scan + scatter ----------------
__global__ __launch_bounds__(256) void k_scan(const int* __restrict__ a, const int* __restrict__ b,
                                              int* aoff, int* boff, int* acur, int* bcur) {
    __shared__ int pa[256], pb[256];
    int t = threadIdx.x;
    const int CH = NN / 256;   // 200
    int base = t * CH;
    int s0 = 0, s1 = 0;
    for (int i = 0; i < CH; i++) { s0 += a[base + i]; s1 += b[base + i]; }
    pa[t] = s0; pb[t] = s1; __syncthreads();
    for (int off = 1; off < 256; off <<= 1) {
        int va = (t >= off) ? pa[t - off] : 0;
        int vb = (t >= off) ? pb[t - off] : 0;
        __syncthreads();
        pa[t] += va; pb[t] += vb;
        __syncthreads();
    }
    int ra = pa[t] - s0, rb = pb[t] - s1;
    for (int i = 0; i < CH; i++) {
        aoff[base + i] = ra; acur[base + i] = ra; ra += a[base + i];
        boff[base + i] = rb; bcur[base + i] = rb; rb += b[base + i];
    }
    if (t == 255) { aoff[NN] = ra; boff[NN] = rb; }
}

__global__ __launch_bounds__(256) void k_scatter(const int* __restrict__ ei, int* scur, int* dcur,
                                                 int* slist, int* dlist) {
    int e = blockIdx.x * 256 + threadIdx.x;
    if (e >= EE) return;
    int s = ei[e], d = ei[EE + e];
    slist[atomicAdd(&scur[s], 1)] = e;
    dlist[atomicAdd(&dcur[d], 1)] = e;
}

// ---------------- per-combo MLP pipeline ----------------
__global__ __launch_bounds__(256) void k_combos1(const float* __restrict__ We1, const float* __restrict__ be1,
                                                 const int* __restrict__ hist, const int* __restrict__ ntcnt,
                                                 float* __restrict__ h1, float* bn1) {
    int c = blockIdx.x, d = threadIdx.x;
    if (d >= D) return;
    float v, w;
    if (c < NC) {
        int etp = c >> 4, ts = (c >> 2) & 3, td = c & 3;
        v = We1[etp*D + d] + We1[(39+ts)*D + d] + We1[(43+td)*D + d] + be1[d];
        w = (float)hist[c];
    } else {
        int t = c - NC;
        v = We1[38*D + d] + We1[(39+t)*D + d] + We1[(43+t)*D + d] + be1[d];
        w = (float)ntcnt[t];
    }
    h1[c*D + d] = v;
    unsafeAtomicAdd(&bn1[d], w * v);
    unsafeAtomicAdd(&bn1[D + d], w * v * v);
}

__global__ __launch_bounds__(256) void k_combos2(const float* __restrict__ h1, const float* __restrict__ bn1,
                                                 const float* __restrict__ ge1, const float* __restrict__ bte1,
                                                 const float* __restrict__ We2, const float* __restrict__ be2,
                                                 float* __restrict__ embE, float* __restrict__ embS) {
    __shared__ float v[D];
    int c = blockIdx.x, t = threadIdx.x;
    if (t < D) {
        float cnt = (float)(EE + NN);
        float m = bn1[t] / cnt;
        float var = bn1[D + t] / cnt - m * m;
        float r = rsqrtf(var + 1e-5f);
        float u = (h1[c*D + t] - m) * r * ge1[t] + bte1[t];
        v[t] = fmaxf(u, 0.f);
    }
    __syncthreads();
    if (t < D) {
        float acc = be2[t];
        for (int k = 0; k < D; k++) acc += v[k] * We2[k*D + t];
        if (c < NC) embE[c*D + t] = acc; else embS[(c-NC)*D + t] = acc;
    }
}

__global__ __launch_bounds__(256) void k_combos3(const float* __restrict__ embE, const float* __restrict__ sumsxf,
                                                 const int* __restrict__ tcnt, const float* __restrict__ Wa1,
                                                 const float* __restrict__ ba1, const int* __restrict__ hist,
                                                 float* __restrict__ h2, float* bn2) {
    __shared__ float a[2*D];
    int c = blockIdx.x, t = threadIdx.x;
    int etp = c >> 4;
    if (t < D) {
        a[t] = embE[c*D + t];
        float cn = fmaxf((float)tcnt[etp], 1.f);
        a[D + t] = sumsxf[etp*D + t] / cn;
    }
    __syncthreads();
    if (t < D) {
        float acc = ba1[t];
        for (int k = 0; k < 2*D; k++) acc += a[k] * Wa1[k*D + t];
        h2[c*D + t] = acc;
        float w = (float)hist[c];
        unsafeAtomicAdd(&bn2[t], w * acc);
        unsafeAtomicAdd(&bn2[D + t], w * acc * acc);
    }
}

__global__ __launch_bounds__(256) void k_combos4(const float* __restrict__ h2, const float* __restrict__ bn2,
                                                 const float* __restrict__ ga1, const float* __restrict__ bta1,
                                                 const float* __restrict__ Wa2, const float* __restrict__ ba2,
                                                 float* __restrict__ Rc) {
    __shared__ float v[D];
    int c = blockIdx.x, t = threadIdx.x;
    if (t < D) {
        float inv = 1.f / (float)EE;
        float m = bn2[t] * inv;
        float var = bn2[D + t] * inv - m * m;
        float r = rsqrtf(var + 1e-5f);
        float u = (h2[c*D + t] - m) * r * ga1[t] + bta1[t];
        v[t] = fmaxf(u, 0.f);
    }
    __syncthreads();
    if (t < D) {
        float acc = ba2[t];
        for (int k = 0; k < D; k++) acc += v[k] * Wa2[k*D + t];
        Rc[c*D + t] = acc;
    }
}

// ---------------- per-graph attention over R ----------------
__global__ __launch_bounds__(256) void k_attn(const float* __restrict__ sent, const float* __restrict__ Watt,
                                              const float* __restrict__ Rc, const unsigned short* __restrict__ combo,
                                              float* __restrict__ upd) {
    __shared__ float q[D];
    __shared__ float sex[LG];
    __shared__ unsigned short cl[LG];
    __shared__ float red[8];
    int b = blockIdx.x, t = threadIdx.x;
    if (t < D) {
        float acc = 0.f;
        for (int k = 0; k < D; k++) acc += sent[b*D + k] * Watt[k*D + t];
        q[t] = acc;
    }
    for (int l = t; l < LG; l += 256) cl[l] = combo[b*LG + l];
    __syncthreads();
    int wave = t >> 6, lane = t & 63;
    const float scale = rsqrtf((float)D);
    for (int l = wave; l < LG; l += 4) {
        const float* r = Rc + cl[l] * D;
        float p = 0.f;
        for (int dd = lane; dd < D; dd += 64) p += q[dd] * r[dd];
        for (int o = 32; o; o >>= 1) p += __shfl_xor(p, o);
        if (lane == 0) sex[l] = p * scale;
    }
    __syncthreads();
    float mx = -1e30f;
    for (int l = t; l < LG; l += 256) mx = fmaxf(mx, sex[l]);
    for (int o = 32; o; o >>= 1) mx = fmaxf(mx, __shfl_xor(mx, o));
    if (lane == 0) red[wave] = mx;
    __syncthreads();
    mx = fmaxf(fmaxf(red[0], red[1]), fmaxf(red[2], red[3]));
    __syncthreads();
    float sm = 0.f;
    for (int l = t; l < LG; l += 256) { float e2 = __expf(sex[l] - mx); sex[l] = e2; sm += e2; }
    for (int o = 32; o; o >>= 1) sm += __shfl_xor(sm, o);
    if (lane == 0) red[4 + wave] = sm;
    __syncthreads();
    float inv = 1.f / (red[4] + red[5] + red[6] + red[7]);
    if (t < D) {
        float acc = 0.f;
        for (int l = 0; l < LG; l++) acc += sex[l] * Rc[cl[l]*D + t];
        upd[b*D + t] = acc * inv;
    }
}

// ---------------- GK/GM (per graph) and SK/SM (per node type) ----------------
__global__ __launch_bounds__(256) void k_gkgm(const float* __restrict__ upd, const float* __restrict__ embS,
                                              const float* __restrict__ Wk, const float* __restrict__ bk,
                                              const float* __restrict__ Wm, const float* __restrict__ bm,
                                              float* GK, float* GM, float* SK, float* SM) {
    __shared__ float v[D];
    int bI = blockIdx.x, t = threadIdx.x;
    const float* in = (bI < BG) ? (upd + bI*D) : (embS + (bI - BG)*D);
    if (t < D) v[t] = in[t];
    __syncthreads();
    if (t < D) {
        float a1 = bk[t], a2 = bm[t];
        for (int k = 0; k < D; k++) {
            a1 += v[k] * Wk[(D + k)*D + t];
            a2 += v[k] * Wm[(D + k)*D + t];
        }
        if (bI < BG) { GK[bI*D + t] = a1; GM[bI*D + t] = a2; }
        else         { SK[(bI-BG)*D + t] = a1; SM[(bI-BG)*D + t] = a2; }
    }
}

// ---------------- fused x @ {Wk[:D], Wm[:D], Wq} ----------------
__global__ __launch_bounds__(256) void k_mm3(const float* __restrict__ A,
                                             const float* __restrict__ Wkp, const float* __restrict__ Wmp,
                                             const float* __restrict__ Wqp, const float* __restrict__ bq,
                                             float* __restrict__ XK, float* __restrict__ XM, float* __restrict__ XQ) {
    __shared__ float aT[D * 68];
    int t = threadIdx.x;
    int n0 = blockIdx.x * 64;
    for (int f = t; f < 64 * D; f += 256) {
        int r = f / D, k = f - r * D;
        aT[k * 68 + r] = A[(size_t)(n0 + r) * D + k];
    }
    __syncthreads();
    if (t >= 200) return;
    int rg = t / 25, cg = t - (t / 25) * 25;
    int r0 = rg * 8, c0 = cg * 8;
    for (int m = 0; m < 3; m++) {
        const float* W = (m == 0) ? Wkp : (m == 1) ? Wmp : Wqp;
        float* C = (m == 0) ? XK : (m == 1) ? XM : XQ;
        float ps = (m == 2) ? 0.14142135623730950488f : 1.f;
        float acc[8][8];
        #pragma unroll
        for (int i = 0; i < 8; i++)
            #pragma unroll
            for (int j = 0; j < 8; j++) acc[i][j] = 0.f;
        for (int k = 0; k < D; k++) {
            const float4 a0 = *(const float4*)&aT[k * 68 + r0];
            const float4 a1 = *(const float4*)&aT[k * 68 + r0 + 4];
            const float4 w0 = *(const float4*)&W[k * D + c0];
            const float4 w1 = *(const float4*)&W[k * D + c0 + 4];
            float av[8] = {a0.x, a0.y, a0.z, a0.w, a1.x, a1.y, a1.z, a1.w};
            float wv[8] = {w0.x, w0.y, w0.z, w0.w, w1.x, w1.y, w1.z, w1.w};
            #pragma unroll
            for (int i = 0; i < 8; i++)
                #pragma unroll
                for (int j = 0; j < 8; j++) acc[i][j] += av[i] * wv[j];
        }
        float bj[8];
        #pragma unroll
        for (int j = 0; j < 8; j++) bj[j] = (m == 2) ? bq[c0 + j] : 0.f;
        #pragma unroll
        for (int i = 0; i < 8; i++) {
            size_t row = (size_t)(n0 + r0 + i);
            float4 o0, o1;
            o0.x = (acc[i][0] + bj[0]) * ps; o0.y = (acc[i][1] + bj[1]) * ps;
            o0.z = (acc[i][2] + bj[2]) * ps; o0.w = (acc[i][3] + bj[3]) * ps;
            o1.x = (acc[i][4] + bj[4]) * ps; o1.y = (acc[i][5] + bj[5]) * ps;
            o1.z = (acc[i][6] + bj[6]) * ps; o1.w = (acc[i][7] + bj[7]) * ps;
            *(float4*)&C[row * D + c0]     = o0;
            *(float4*)&C[row * D + c0 + 4] = o1;
        }
    }
}

// ---------------- generic NNx200 @ 200x200 matmul ----------------
__global__ __launch_bounds__(256) void k_mm200(const float* __restrict__ A, const float* __restrict__ W,
                                               const float* __restrict__ bias, float* __restrict__ C,
                                               int preop, const float* __restrict__ bnacc, float invCnt,
                                               const float* __restrict__ g, const float* __restrict__ bb,
                                               float postscale) {
    __shared__ float aT[D * 68];
    __shared__ float scl[D], sft[D];
    int t = threadIdx.x;
    int n0 = blockIdx.x * 64;
    if (preop) {
        if (t < D) {
            float m = bnacc[t] * invCnt;
            float var = bnacc[D + t] * invCnt - m * m;
            float rs = rsqrtf(var + 1e-5f);
            float s = rs * g[t];
            scl[t] = s;
            sft[t] = bb[t] - m * s;
        }
        __syncthreads();
    }
    for (int f = t; f < 64 * D; f += 256) {
        int r = f / D, k = f - r * D;
        float v = A[(size_t)(n0 + r) * D + k];
        if (preop) v = fmaxf(v * scl[k] + sft[k], 0.f);
        aT[k * 68 + r] = v;
    }
    __syncthreads();
    if (t < 200) {
        int rg = t / 25, cg = t - (t / 25) * 25;
        int r0 = rg * 8, c0 = cg * 8;
        float acc[8][8];
        #pragma unroll
        for (int i = 0; i < 8; i++)
            #pragma unroll
            for (int j = 0; j < 8; j++) acc[i][j] = 0.f;
        for (int k = 0; k < D; k++) {
            const float4 a0 = *(const float4*)&aT[k * 68 + r0];
            const float4 a1 = *(const float4*)&aT[k * 68 + r0 + 4];
            const float4 w0 = *(const float4*)&W[k * D + c0];
            const float4 w1 = *(const float4*)&W[k * D + c0 + 4];
            float av[8] = {a0.x, a0.y, a0.z, a0.w, a1.x, a1.y, a1.z, a1.w};
            float wv[8] = {w0.x, w0.y, w0.z, w0.w, w1.x, w1.y, w1.z, w1.w};
            #pragma unroll
            for (int i = 0; i < 8; i++)
                #pragma unroll
                for (int j = 0; j < 8; j++) acc[i][j] += av[i] * wv[j];
        }
        float bj[8];
        #pragma unroll
        for (int j = 0; j < 8; j++) bj[j] = bias ? bias[c0 + j] : 0.f;
        #pragma unroll
        for (int i = 0; i < 8; i++) {
            size_t row = (size_t)(n0 + r0 + i);
            float4 o0, o1;
            o0.x = (acc[i][0] + bj[0]) * postscale; o0.y = (acc[i][1] + bj[1]) * postscale;
            o0.z = (acc[i][2] + bj[2]) * postscale; o0.w = (acc[i][3] + bj[3]) * postscale;
            o1.x = (acc[i][4] + bj[4]) * postscale; o1.y = (acc[i][5] + bj[5]) * postscale;
            o1.z = (acc[i][6] + bj[6]) * postscale; o1.w = (acc[i][7] + bj[7]) * postscale;
            *(float4*)&C[row * D + c0]     = o0;
            *(float4*)&C[row * D + c0 + 4] = o1;
        }
    }
}

// ---------------- edge softmax, src-CSR, wave per node, no atomics ----------------
__global__ __launch_bounds__(256) void k_soft(const int* __restrict__ ei, const int* __restrict__ nt,
                                              const int* __restrict__ soff, const int* __restrict__ slist,
                                              const int* __restrict__ outdeg,
                                              const float* __restrict__ XQ, const float* __restrict__ XK,
                                              const float* __restrict__ GK, const float* __restrict__ SK,
                                              float* __restrict__ sc, float* __restrict__ scale) {
    int wave = threadIdx.x >> 6, lane = threadIdx.x & 63;
    int n = blockIdx.x * 4 + wave;
    if (n >= NN) return;
    float qv[4];
    #pragma unroll
    for (int j = 0; j < 4; j++) { int dd = lane + 64*j; qv[j] = (dd < D) ? XQ[(size_t)n*D + dd] : 0.f; }
    float den0 = 0.f, den1 = 0.f, den2 = 0.f, den3 = 0.f;
    // self entry
    {
        int tn = nt[n];
        float h0 = 0, h1 = 0, h2 = 0, h3 = 0;
        #pragma unroll
        for (int j = 0; j < 4; j++) {
            int dd = lane + 64*j;
            if (dd < D) {
                float p = qv[j] * (XK[(size_t)n*D + dd] + SK[tn*D + dd]);
                int hh = dd / DH;
                if (hh == 0) h0 += p; else if (hh == 1) h1 += p; else if (hh == 2) h2 += p; else h3 += p;
            }
        }
        for (int o = 32; o; o >>= 1) {
            h0 += __shfl_xor(h0, o); h1 += __shfl_xor(h1, o);
            h2 += __shfl_xor(h2, o); h3 += __shfl_xor(h3, o);
        }
        float e0 = __expf(h0), e1 = __expf(h1), e2 = __expf(h2), e3 = __expf(h3);
        den0 += e0; den1 += e1; den2 += e2; den3 += e3;
        if (lane < 4) {
            float v = (lane == 0) ? e0 : (lane == 1) ? e1 : (lane == 2) ? e2 : e3;
            sc[(size_t)(EE + n) * 4 + lane] = v;
        }
    }
    int beg = soff[n], end = soff[n + 1];
    for (int i = beg; i < end; i++) {
        int e = slist[i];
        int tail = ei[EE + e];
        int g = e >> 10;
        float h0 = 0, h1 = 0, h2 = 0, h3 = 0;
        #pragma unroll
        for (int j = 0; j < 4; j++) {
            int dd = lane + 64*j;
            if (dd < D) {
                float p = qv[j] * (XK[(size_t)tail*D + dd] + GK[g*D + dd]);
                int hh = dd / DH;
                if (hh == 0) h0 += p; else if (hh == 1) h1 += p; else if (hh == 2) h2 += p; else h3 += p;
            }
        }
        for (int o = 32; o; o >>= 1) {
            h0 += __shfl_xor(h0, o); h1 += __shfl_xor(h1, o);
            h2 += __shfl_xor(h2, o); h3 += __shfl_xor(h3, o);
        }
        float e0 = __expf(h0), e1 = __expf(h1), e2 = __expf(h2), e3 = __expf(h3);
        den0 += e0; den1 += e1; den2 += e2; den3 += e3;
        if (lane < 4) {
            float v = (lane == 0) ? e0 : (lane == 1) ? e1 : (lane == 2) ? e2 : e3;
            sc[(size_t)e * 4 + lane] = v;
        }
    }
    float cnt = (float)(outdeg[n] + 1);
    if (lane < 4) {
        float dn = (lane == 0) ? den0 : (lane == 1) ? den1 : (lane == 2) ? den2 : den3;
        scale[(size_t)n * 4 + lane] = cnt / dn;
    }
}

// ---------------- aggregation, dst-CSR, wave per node, no atomics ----------------
__global__ __launch_bounds__(256) void k_aggr(const int* __restrict__ ei, const int* __restrict__ nt,
                                              const int* __restrict__ doff, const int* __restrict__ dlist,
                                              const float* __restrict__ sc, const float* __restrict__ scale,
                                              const float* __restrict__ XM, const float* __restrict__ GM,
                                              const float* __restrict__ SM, float* __restrict__ aggr) {
    int wave = threadIdx.x >> 6, lane = threadIdx.x & 63;
    int n = blockIdx.x * 4 + wave;
    if (n >= NN) return;
    float acc[4] = {0.f, 0.f, 0.f, 0.f};
    // self message
    {
        int tn = nt[n];
        float4 ss = *(const float4*)&sc[(size_t)(EE + n) * 4];
        float4 sl = *(const float4*)&scale[(size_t)n * 4];
        float a0 = ss.x * sl.x, a1 = ss.y * sl.y, a2 = ss.z * sl.z, a3 = ss.w * sl.w;
        #pragma unroll
        for (int j = 0; j < 4; j++) {
            int dd = lane + 64*j;
            if (dd < D) {
                float al = (dd < DH) ? a0 : (dd < 2*DH) ? a1 : (dd < 3*DH) ? a2 : a3;
                acc[j] += al * (XM[(size_t)n*D + dd] + SM[tn*D + dd]);
            }
        }
    }
    int beg = doff[n], end = doff[n + 1];
    for (int i = beg; i < end; i++) {
        int e = dlist[i];
        int s = ei[e];
        int g = e >> 10;
        float4 ss = *(const float4*)&sc[(size_t)e * 4];
        float4 sl = *(const float4*)&scale[(size_t)s * 4];
        float a0 = ss.x * sl.x, a1 = ss.y * sl.y, a2 = ss.z * sl.z, a3 = ss.w * sl.w;
        #pragma unroll
        for (int j = 0; j < 4; j++) {
            int dd = lane + 64*j;
            if (dd < D) {
                float al = (dd < DH) ? a0 : (dd < 2*DH) ? a1 : (dd < 3*DH) ? a2 : a3;
                acc[j] += al * (XM[(size_t)s*D + dd] + GM[g*D + dd]);
            }
        }
    }
    #pragma unroll
    for (int j = 0; j < 4; j++) {
        int dd = lane + 64*j;
        if (dd < D) aggr[(size_t)n*D + dd] = acc[j];
    }
}

// ---------------- column stats for final BN ----------------
__global__ __launch_bounds__(256) void k_colstats(const float* __restrict__ T1, float* bn3) {
    int t = threadIdx.x;
    if (t >= D) return;
    int r0 = blockIdx.x * 256;
    float s = 0.f, q = 0.f;
    for (int r = r0; r < r0 + 256; r++) {
        float v = T1[(size_t)r * D + t];
        s += v; q += v * v;
    }
    unsafeAtomicAdd(&bn3[t], s);
    unsafeAtomicAdd(&bn3[D + t], q);
}

extern "C" void kernel_launch(void* const* d_in, const int* in_sizes, int n_in,
                              void* d_out, int out_size, void* d_ws, size_t ws_size,
                              hipStream_t stream) {
    const float* x    = (const float*)d_in[0];
    const float* sent = (const float*)d_in[2];
    const float* We1  = (const float*)d_in[3];
    const float* be1  = (const float*)d_in[4];
    const float* ge1  = (const float*)d_in[5];
    const float* bte1 = (const float*)d_in[6];
    const float* We2  = (const float*)d_in[7];
    const float* be2  = (const float*)d_in[8];
    const float* Wa1  = (const float*)d_in[9];
    const float* ba1  = (const float*)d_in[10];
    const float* ga1  = (const float*)d_in[11];
    const float* bta1 = (const float*)d_in[12];
    const float* Wa2  = (const float*)d_in[13];
    const float* ba2  = (const float*)d_in[14];
    const float* Watt = (const float*)d_in[15];
    const float* Wk   = (const float*)d_in[16];
    const float* bk   = (const float*)d_in[17];
    const float* Wm   = (const float*)d_in[18];
    const float* bm   = (const float*)d_in[19];
    const float* Wq   = (const float*)d_in[20];
    const float* bq   = (const float*)d_in[21];
    const float* Wo1  = (const float*)d_in[22];
    const float* bo1  = (const float*)d_in[23];
    const float* go1  = (const float*)d_in[24];
    const float* bto1 = (const float*)d_in[25];
    const float* Wo2  = (const float*)d_in[26];
    const float* bo2  = (const float*)d_in[27];
    const int* ei = (const int*)d_in[28];
    const int* et = (const int*)d_in[29];
    const int* nt = (const int*)d_in[30];

    char* ws = (char*)d_ws;
    size_t off = 0;
    auto alloc = [&](size_t bytes) -> char* {
        char* p = ws + off;
        off = (off + bytes + 255) & ~(size_t)255;
        return p;
    };
    // ---- zeroed region ----
    int*   hist   = (int*)  alloc(NC * 4);
    int*   ntcnt  = (int*)  alloc(NTY * 4);
    float* bn1    = (float*)alloc(2 * D * 4);
    float* bn2    = (float*)alloc(2 * D * 4);
    float* bn3    = (float*)alloc(2 * D * 4);
    float* sumsxf = (float*)alloc(NE * D * 4);
    int*   outdeg = (int*)  alloc(NN * 4);
    int*   indeg  = (int*)  alloc(NN * 4);
    size_t zero_end = off;
    // ---- rest ----
    int* tcnt = (int*)alloc(NE * 4);
    int* soff_ = (int*)alloc((NN + 1) * 4);
    int* doff_ = (int*)alloc((NN + 1) * 4);
    int* scur = (int*)alloc(NN * 4);
    int* dcur = (int*)alloc(NN * 4);
    int* slist = (int*)alloc((size_t)EE * 4);
    int* dlist = (int*)alloc((size_t)EE * 4);
    unsigned short* combo = (unsigned short*)alloc((size_t)EE * 2);
    float* h1v   = (float*)alloc((size_t)NCT * D * 4);
    float* embE  = (float*)alloc((size_t)NC * D * 4);
    float* embS  = (float*)alloc((size_t)NTY * D * 4);
    float* h2pre = (float*)alloc((size_t)NC * D * 4);
    float* Rc    = (float*)alloc((size_t)NC * D * 4);
    float* upd   = (float*)alloc((size_t)BG * D * 4);
    float* GK    = (float*)alloc((size_t)BG * D * 4);
    float* GM    = (float*)alloc((size_t)BG * D * 4);
    float* SK    = (float*)alloc((size_t)NTY * D * 4);
    float* SM    = (float*)alloc((size_t)NTY * D * 4);
    float* sc    = (float*)alloc((size_t)EA * H * 4);
    float* XK    = (float*)alloc((size_t)NN * D * 4);
    float* XM    = (float*)alloc((size_t)NN * D * 4);
    float* XQ    = (float*)alloc((size_t)NN * D * 4);
    // aliases (liveness-checked):
    float* coef  = XK;            // dead before k_mm3 writes XK
    float* scale = h1v;           // h1v+embE dead long before k_soft writes scale (needs 819KB < 976KB)
    float* aggr  = XQ;            // XQ dead after k_soft
    float* T1    = XK;            // XK dead after k_soft

    hipMemsetAsync(ws, 0, zero_end, stream);
    hipMemsetAsync(coef, 0, (size_t)NN * NE * 4, stream);

    k_hist   <<<EE / 256, 256, 0, stream>>>(ei, et, nt, hist, outdeg, indeg, combo);
    k_ntcnt  <<<NN / 256, 256, 0, stream>>>(nt, ntcnt);
    k_coef   <<<EE / 256, 256, 0, stream>>>(ei, et, coef);
    k_tcnt   <<<1, 64, 0, stream>>>(hist, tcnt);
    k_scan   <<<1, 256, 0, stream>>>(outdeg, indeg, soff_, doff_, scur, dcur);
    k_scatter<<<EE / 256, 256, 0, stream>>>(ei, scur, dcur, slist, dlist);
    k_xfsum2 <<<128, 256, 0, stream>>>(x, coef, sumsxf);
    k_combos1<<<NCT, 256, 0, stream>>>(We1, be1, hist, ntcnt, h1v, bn1);
    k_combos2<<<NCT, 256, 0, stream>>>(h1v, bn1, ge1, bte1, We2, be2, embE, embS);
    k_combos3<<<NC, 256, 0, stream>>>(embE, sumsxf, tcnt, Wa1, ba1, hist, h2pre, bn2);
    k_combos4<<<NC, 256, 0, stream>>>(h2pre, bn2, ga1, bta1, Wa2, ba2, Rc);
    k_attn   <<<BG, 256, 0, stream>>>(sent, Watt, Rc, combo, upd);
    k_gkgm   <<<BG + NTY, 256, 0, stream>>>(upd, embS, Wk, bk, Wm, bm, GK, GM, SK, SM);
    k_mm3    <<<NN / 64, 256, 0, stream>>>(x, Wk, Wm, Wq, bq, XK, XM, XQ);
    k_soft   <<<NN / 4, 256, 0, stream>>>(ei, nt, soff_, slist, outdeg, XQ, XK, GK, SK, sc, scale);
    k_aggr   <<<NN / 4, 256, 0, stream>>>(ei, nt, doff_, dlist, sc, scale, XM, GM, SM, aggr);
    k_mm200  <<<NN / 64, 256, 0, stream>>>(aggr, Wo1, bo1, T1, 0, nullptr, 0.f, nullptr, nullptr, 1.f);
    k_colstats<<<NN / 256, 256, 0, stream>>>(T1, bn3);
    k_mm200  <<<NN / 64, 256, 0, stream>>>(T1, Wo2, bo2, (float*)d_out, 1, bn3, 1.f / (float)NN, go1, bto1, 1.f);
}

// Round 3
// 1867.567 us; speedup vs baseline: 1.4517x; 1.4517x over previous
//
#include <hip/hip_runtime.h>

#define D     200
#define H     4
#define DH    50
#define NE    38
#define NTY   4
#define NC    608      // edge combos = 38*4*4
#define NCT   612      // + 4 self combos
#define BG    256      // graphs
#define LG    1024     // edges per graph
#define EE    262144   // E
#define NN    51200    // N
#define EA    313344   // E + N

// ---------------- histogram / combo / degrees ----------------
__global__ __launch_bounds__(256) void k_hist(const int* __restrict__ ei, const int* __restrict__ et,
                                              const int* __restrict__ nt, int* hist, int* outdeg, int* indeg,
                                              unsigned short* __restrict__ combo) {
    int e = blockIdx.x * 256 + threadIdx.x;
    if (e >= EE) return;
    int s = ei[e], d = ei[EE + e];
    int c = et[e] * 16 + nt[s] * 4 + nt[d];
    combo[e] = (unsigned short)c;
    atomicAdd(&hist[c], 1);
    atomicAdd(&outdeg[s], 1);
    atomicAdd(&indeg[d], 1);
}

__global__ __launch_bounds__(256) void k_ntcnt(const int* __restrict__ nt, int* ntcnt) {
    int n = blockIdx.x * 256 + threadIdx.x;
    if (n < NN) atomicAdd(&ntcnt[nt[n]], 1);
}

__global__ void k_tcnt(const int* __restrict__ hist, int* tcnt) {
    int t = threadIdx.x;
    if (t < NE) { int s = 0; for (int i = 0; i < 16; i++) s += hist[t*16 + i]; tcnt[t] = s; }
}

// ---------------- per-(node,type) signed coefficients ----------------
__global__ __launch_bounds__(256) void k_coef(const int* __restrict__ ei, const int* __restrict__ et,
                                              float* coef) {
    int e = blockIdx.x * 256 + threadIdx.x;
    if (e >= EE) return;
    int s = ei[e], d = ei[EE + e], t = et[e];
    unsafeAtomicAdd(&coef[(size_t)d * NE + t],  1.f);
    unsafeAtomicAdd(&coef[(size_t)s * NE + t], -1.f);
}

// sums = coef^T (38 x NN) @ x (NN x 200), K-split GEMM.
// Thread t<200 owns column t; 38 accumulators in VGPRs; coef loads are
// wave-uniform -> scalar loads. One coalesced x load per k.
__global__ __launch_bounds__(256) void k_xfsum3(const float* __restrict__ x, const float* __restrict__ coef,
                                                float* sums) {
    const int CH = NN / 256;   // 200 nodes per block
    int t = threadIdx.x;
    int n0 = blockIdx.x * CH;
    float acc[NE];
    #pragma unroll
    for (int m = 0; m < NE; m++) acc[m] = 0.f;
    if (t < D) {
        for (int k = 0; k < CH; k++) {
            int n = n0 + k;
            float xv = x[(size_t)n * D + t];
            const float* cf = coef + (size_t)n * NE;
            #pragma unroll
            for (int m = 0; m < NE; m++) acc[m] += cf[m] * xv;
        }
        #pragma unroll
        for (int m = 0; m < NE; m++)
            if (acc[m] != 0.f) unsafeAtomicAdd(&sums[m * D + t], acc[m]);
    }
}

// ---------------- CSR build: scan + scatter ----------------
__global__ __launch_bounds__(256) void k_scan(const int* __restrict__ a, const int* __restrict__ b,
                                              int* aoff, int* boff, int* acur, int* bcur) {
    __shared__ int pa[256], pb[256];
    int t = threadIdx.x;
    const int CH = NN / 256;   // 200
    int base = t * CH;
    int s0 = 0, s1 = 0;
    for (int i = 0; i < CH; i++) { s0 += a[base + i]; s1 += b[base + i]; }
    pa[t] = s0; pb[t] = s1; __syncthreads();
    for (int off = 1; off < 256; off <<= 1) {
        int va = (t >= off) ? pa[t - off] : 0;
        int vb = (t >= off) ? pb[t - off] : 0;
        __syncthreads();
        pa[t] += va; pb[t] += vb;
        __syncthreads();
    }
    int ra = pa[t] - s0, rb = pb[t] - s1;
    for (int i = 0; i < CH; i++) {
        aoff[base + i] = ra; acur[base + i] = ra; ra += a[base + i];
        boff[base + i] = rb; bcur[base + i] = rb; rb += b[base + i];
    }
    if (t == 255) { aoff[NN] = ra; boff[NN] = rb; }
}

__global__ __launch_bounds__(256) void k_scatter(const int* __restrict__ ei, int* scur, int* dcur,
                                                 int* slist, int* dlist) {
    int e = blockIdx.x * 256 + threadIdx.x;
    if (e >= EE) return;
    int s = ei[e], d = ei[EE + e];
    slist[atomicAdd(&scur[s], 1)] = e;
    dlist[atomicAdd(&dcur[d], 1)] = e;
}

// ---------------- per-combo MLP pipeline ----------------
__global__ __launch_bounds__(256) void k_combos1(const float* __restrict__ We1, const float* __restrict__ be1,
                                                 const int* __restrict__ hist, const int* __restrict__ ntcnt,
                                                 float* __restrict__ h1, float* bn1) {
    int c = blockIdx.x, d = threadIdx.x;
    if (d >= D) return;
    float v, w;
    if (c < NC) {
        int etp = c >> 4, ts = (c >> 2) & 3, td = c & 3;
        v = We1[etp*D + d] + We1[(39+ts)*D + d] + We1[(43+td)*D + d] + be1[d];
        w = (float)hist[c];
    } else {
        int t = c - NC;
        v = We1[38*D + d] + We1[(39+t)*D + d] + We1[(43+t)*D + d] + be1[d];
        w = (float)ntcnt[t];
    }
    h1[c*D + d] = v;
    unsafeAtomicAdd(&bn1[d], w * v);
    unsafeAtomicAdd(&bn1[D + d], w * v * v);
}

__global__ __launch_bounds__(256) void k_combos2(const float* __restrict__ h1, const float* __restrict__ bn1,
                                                 const float* __restrict__ ge1, const float* __restrict__ bte1,
                                                 const float* __restrict__ We2, const float* __restrict__ be2,
                                                 float* __restrict__ embE, float* __restrict__ embS) {
    __shared__ float v[D];
    int c = blockIdx.x, t = threadIdx.x;
    if (t < D) {
        float cnt = (float)(EE + NN);
        float m = bn1[t] / cnt;
        float var = bn1[D + t] / cnt - m * m;
        float r = rsqrtf(var + 1e-5f);
        float u = (h1[c*D + t] - m) * r * ge1[t] + bte1[t];
        v[t] = fmaxf(u, 0.f);
    }
    __syncthreads();
    if (t < D) {
        float acc = be2[t];
        for (int k = 0; k < D; k++) acc += v[k] * We2[k*D + t];
        if (c < NC) embE[c*D + t] = acc; else embS[(c-NC)*D + t] = acc;
    }
}

__global__ __launch_bounds__(256) void k_combos3(const float* __restrict__ embE, const float* __restrict__ sumsxf,
                                                 const int* __restrict__ tcnt, const float* __restrict__ Wa1,
                                                 const float* __restrict__ ba1, const int* __restrict__ hist,
                                                 float* __restrict__ h2, float* bn2) {
    __shared__ float a[2*D];
    int c = blockIdx.x, t = threadIdx.x;
    int etp = c >> 4;
    if (t < D) {
        a[t] = embE[c*D + t];
        float cn = fmaxf((float)tcnt[etp], 1.f);
        a[D + t] = sumsxf[etp*D + t] / cn;
    }
    __syncthreads();
    if (t < D) {
        float acc = ba1[t];
        for (int k = 0; k < 2*D; k++) acc += a[k] * Wa1[k*D + t];
        h2[c*D + t] = acc;
        float w = (float)hist[c];
        unsafeAtomicAdd(&bn2[t], w * acc);
        unsafeAtomicAdd(&bn2[D + t], w * acc * acc);
    }
}

__global__ __launch_bounds__(256) void k_combos4(const float* __restrict__ h2, const float* __restrict__ bn2,
                                                 const float* __restrict__ ga1, const float* __restrict__ bta1,
                                                 const float* __restrict__ Wa2, const float* __restrict__ ba2,
                                                 float* __restrict__ Rc) {
    __shared__ float v[D];
    int c = blockIdx.x, t = threadIdx.x;
    if (t < D) {
        float inv = 1.f / (float)EE;
        float m = bn2[t] * inv;
        float var = bn2[D + t] * inv - m * m;
        float r = rsqrtf(var + 1e-5f);
        float u = (h2[c*D + t] - m) * r * ga1[t] + bta1[t];
        v[t] = fmaxf(u, 0.f);
    }
    __syncthreads();
    if (t < D) {
        float acc = ba2[t];
        for (int k = 0; k < D; k++) acc += v[k] * Wa2[k*D + t];
        Rc[c*D + t] = acc;
    }
}

// ---------------- per-graph attention over R ----------------
__global__ __launch_bounds__(256) void k_attn(const float* __restrict__ sent, const float* __restrict__ Watt,
                                              const float* __restrict__ Rc, const unsigned short* __restrict__ combo,
                                              float* __restrict__ upd) {
    __shared__ float q[D];
    __shared__ float sex[LG];
    __shared__ unsigned short cl[LG];
    __shared__ float red[8];
    __shared__ float part[4][D];
    int b = blockIdx.x, t = threadIdx.x;
    if (t < D) {
        float acc = 0.f;
        for (int k = 0; k < D; k++) acc += sent[b*D + k] * Watt[k*D + t];
        q[t] = acc;
    }
    for (int l = t; l < LG; l += 256) cl[l] = combo[b*LG + l];
    __syncthreads();
    int wave = t >> 6, lane = t & 63;
    const float scale = rsqrtf((float)D);
    for (int l = wave; l < LG; l += 4) {
        const float* r = Rc + cl[l] * D;
        float p = 0.f;
        for (int dd = lane; dd < D; dd += 64) p += q[dd] * r[dd];
        for (int o = 32; o; o >>= 1) p += __shfl_xor(p, o);
        if (lane == 0) sex[l] = p * scale;
    }
    __syncthreads();
    float mx = -1e30f;
    for (int l = t; l < LG; l += 256) mx = fmaxf(mx, sex[l]);
    for (int o = 32; o; o >>= 1) mx = fmaxf(mx, __shfl_xor(mx, o));
    if (lane == 0) red[wave] = mx;
    __syncthreads();
    mx = fmaxf(fmaxf(red[0], red[1]), fmaxf(red[2], red[3]));
    __syncthreads();
    float sm = 0.f;
    for (int l = t; l < LG; l += 256) { float e2 = __expf(sex[l] - mx); sex[l] = e2; sm += e2; }
    for (int o = 32; o; o >>= 1) sm += __shfl_xor(sm, o);
    if (lane == 0) red[4 + wave] = sm;
    __syncthreads();
    float inv = 1.f / (red[4] + red[5] + red[6] + red[7]);
    // parallel upd accumulation: each wave covers 256 edges, register partials
    float acc[4] = {0.f, 0.f, 0.f, 0.f};
    for (int l = wave * 256; l < wave * 256 + 256; l++) {
        float s = sex[l];
        const float* r = Rc + cl[l] * D;
        #pragma unroll
        for (int j = 0; j < 4; j++) { int dd = lane + 64*j; if (dd < D) acc[j] += s * r[dd]; }
    }
    #pragma unroll
    for (int j = 0; j < 4; j++) { int dd = lane + 64*j; if (dd < D) part[wave][dd] = acc[j]; }
    __syncthreads();
    if (t < D) upd[b*D + t] = (part[0][t] + part[1][t] + part[2][t] + part[3][t]) * inv;
}

// ---------------- GK/GM (per graph) and SK/SM (per node type) ----------------
__global__ __launch_bounds__(256) void k_gkgm(const float* __restrict__ upd, const float* __restrict__ embS,
                                              const float* __restrict__ Wk, const float* __restrict__ bk,
                                              const float* __restrict__ Wm, const float* __restrict__ bm,
                                              float* GK, float* GM, float* SK, float* SM) {
    __shared__ float v[D];
    int bI = blockIdx.x, t = threadIdx.x;
    const float* in = (bI < BG) ? (upd + bI*D) : (embS + (bI - BG)*D);
    if (t < D) v[t] = in[t];
    __syncthreads();
    if (t < D) {
        float a1 = bk[t], a2 = bm[t];
        for (int k = 0; k < D; k++) {
            a1 += v[k] * Wk[(D + k)*D + t];
            a2 += v[k] * Wm[(D + k)*D + t];
        }
        if (bI < BG) { GK[bI*D + t] = a1; GM[bI*D + t] = a2; }
        else         { SK[(bI-BG)*D + t] = a1; SM[(bI-BG)*D + t] = a2; }
    }
}

// ---------------- fused x @ {Wk[:D], Wm[:D], Wq} ----------------
__global__ __launch_bounds__(256) void k_mm3(const float* __restrict__ A,
                                             const float* __restrict__ Wkp, const float* __restrict__ Wmp,
                                             const float* __restrict__ Wqp, const float* __restrict__ bq,
                                             float* __restrict__ XK, float* __restrict__ XM, float* __restrict__ XQ) {
    __shared__ float aT[D * 68];
    int t = threadIdx.x;
    int n0 = blockIdx.x * 64;
    for (int f = t; f < 64 * D; f += 256) {
        int r = f / D, k = f - r * D;
        aT[k * 68 + r] = A[(size_t)(n0 + r) * D + k];
    }
    __syncthreads();
    if (t >= 200) return;
    int rg = t / 25, cg = t - (t / 25) * 25;
    int r0 = rg * 8, c0 = cg * 8;
    for (int m = 0; m < 3; m++) {
        const float* W = (m == 0) ? Wkp : (m == 1) ? Wmp : Wqp;
        float* C = (m == 0) ? XK : (m == 1) ? XM : XQ;
        float ps = (m == 2) ? 0.14142135623730950488f : 1.f;
        float acc[8][8];
        #pragma unroll
        for (int i = 0; i < 8; i++)
            #pragma unroll
            for (int j = 0; j < 8; j++) acc[i][j] = 0.f;
        for (int k = 0; k < D; k++) {
            const float4 a0 = *(const float4*)&aT[k * 68 + r0];
            const float4 a1 = *(const float4*)&aT[k * 68 + r0 + 4];
            const float4 w0 = *(const float4*)&W[k * D + c0];
            const float4 w1 = *(const float4*)&W[k * D + c0 + 4];
            float av[8] = {a0.x, a0.y, a0.z, a0.w, a1.x, a1.y, a1.z, a1.w};
            float wv[8] = {w0.x, w0.y, w0.z, w0.w, w1.x, w1.y, w1.z, w1.w};
            #pragma unroll
            for (int i = 0; i < 8; i++)
                #pragma unroll
                for (int j = 0; j < 8; j++) acc[i][j] += av[i] * wv[j];
        }
        float bj[8];
        #pragma unroll
        for (int j = 0; j < 8; j++) bj[j] = (m == 2) ? bq[c0 + j] : 0.f;
        #pragma unroll
        for (int i = 0; i < 8; i++) {
            size_t row = (size_t)(n0 + r0 + i);
            float4 o0, o1;
            o0.x = (acc[i][0] + bj[0]) * ps; o0.y = (acc[i][1] + bj[1]) * ps;
            o0.z = (acc[i][2] + bj[2]) * ps; o0.w = (acc[i][3] + bj[3]) * ps;
            o1.x = (acc[i][4] + bj[4]) * ps; o1.y = (acc[i][5] + bj[5]) * ps;
            o1.z = (acc[i][6] + bj[6]) * ps; o1.w = (acc[i][7] + bj[7]) * ps;
            *(float4*)&C[row * D + c0]     = o0;
            *(float4*)&C[row * D + c0 + 4] = o1;
        }
    }
}

// ---------------- generic NNx200 @ 200x200 matmul ----------------
__global__ __launch_bounds__(256) void k_mm200(const float* __restrict__ A, const float* __restrict__ W,
                                               const float* __restrict__ bias, float* __restrict__ C,
                                               int preop, const float* __restrict__ bnacc, float invCnt,
                                               const float* __restrict__ g, const float* __restrict__ bb,
                                               float postscale) {
    __shared__ float aT[D * 68];
    __shared__ float scl[D], sft[D];
    int t = threadIdx.x;
    int n0 = blockIdx.x * 64;
    if (preop) {
        if (t < D) {
            float m = bnacc[t] * invCnt;
            float var = bnacc[D + t] * invCnt - m * m;
            float rs = rsqrtf(var + 1e-5f);
            float s = rs * g[t];
            scl[t] = s;
            sft[t] = bb[t] - m * s;
        }
        __syncthreads();
    }
    for (int f = t; f < 64 * D; f += 256) {
        int r = f / D, k = f - r * D;
        float v = A[(size_t)(n0 + r) * D + k];
        if (preop) v = fmaxf(v * scl[k] + sft[k], 0.f);
        aT[k * 68 + r] = v;
    }
    __syncthreads();
    if (t < 200) {
        int rg = t / 25, cg = t - (t / 25) * 25;
        int r0 = rg * 8, c0 = cg * 8;
        float acc[8][8];
        #pragma unroll
        for (int i = 0; i < 8; i++)
            #pragma unroll
            for (int j = 0; j < 8; j++) acc[i][j] = 0.f;
        for (int k = 0; k < D; k++) {
            const float4 a0 = *(const float4*)&aT[k * 68 + r0];
            const float4 a1 = *(const float4*)&aT[k * 68 + r0 + 4];
            const float4 w0 = *(const float4*)&W[k * D + c0];
            const float4 w1 = *(const float4*)&W[k * D + c0 + 4];
            float av[8] = {a0.x, a0.y, a0.z, a0.w, a1.x, a1.y, a1.z, a1.w};
            float wv[8] = {w0.x, w0.y, w0.z, w0.w, w1.x, w1.y, w1.z, w1.w};
            #pragma unroll
            for (int i = 0; i < 8; i++)
                #pragma unroll
                for (int j = 0; j < 8; j++) acc[i][j] += av[i] * wv[j];
        }
        float bj[8];
        #pragma unroll
        for (int j = 0; j < 8; j++) bj[j] = bias ? bias[c0 + j] : 0.f;
        #pragma unroll
        for (int i = 0; i < 8; i++) {
            size_t row = (size_t)(n0 + r0 + i);
            float4 o0, o1;
            o0.x = (acc[i][0] + bj[0]) * postscale; o0.y = (acc[i][1] + bj[1]) * postscale;
            o0.z = (acc[i][2] + bj[2]) * postscale; o0.w = (acc[i][3] + bj[3]) * postscale;
            o1.x = (acc[i][4] + bj[4]) * postscale; o1.y = (acc[i][5] + bj[5]) * postscale;
            o1.z = (acc[i][6] + bj[6]) * postscale; o1.w = (acc[i][7] + bj[7]) * postscale;
            *(float4*)&C[row * D + c0]     = o0;
            *(float4*)&C[row * D + c0 + 4] = o1;
        }
    }
}

// ---------------- edge softmax, src-CSR, wave per node, no atomics ----------------
__global__ __launch_bounds__(256) void k_soft(const int* __restrict__ ei, const int* __restrict__ nt,
                                              const int* __restrict__ soff, const int* __restrict__ slist,
                                              const int* __restrict__ outdeg,
                                              const float* __restrict__ XQ, const float* __restrict__ XK,
                                              const float* __restrict__ GK, const float* __restrict__ SK,
                                              float* __restrict__ sc, float* __restrict__ scale) {
    int wave = threadIdx.x >> 6, lane = threadIdx.x & 63;
    int n = blockIdx.x * 4 + wave;
    if (n >= NN) return;
    float qv[4];
    #pragma unroll
    for (int j = 0; j < 4; j++) { int dd = lane + 64*j; qv[j] = (dd < D) ? XQ[(size_t)n*D + dd] : 0.f; }
    float den0 = 0.f, den1 = 0.f, den2 = 0.f, den3 = 0.f;
    // self entry
    {
        int tn = nt[n];
        float h0 = 0, h1 = 0, h2 = 0, h3 = 0;
        #pragma unroll
        for (int j = 0; j < 4; j++) {
            int dd = lane + 64*j;
            if (dd < D) {
                float p = qv[j] * (XK[(size_t)n*D + dd] + SK[tn*D + dd]);
                int hh = dd / DH;
                if (hh == 0) h0 += p; else if (hh == 1) h1 += p; else if (hh == 2) h2 += p; else h3 += p;
            }
        }
        for (int o = 32; o; o >>= 1) {
            h0 += __shfl_xor(h0, o); h1 += __shfl_xor(h1, o);
            h2 += __shfl_xor(h2, o); h3 += __shfl_xor(h3, o);
        }
        float e0 = __expf(h0), e1 = __expf(h1), e2 = __expf(h2), e3 = __expf(h3);
        den0 += e0; den1 += e1; den2 += e2; den3 += e3;
        if (lane < 4) {
            float v = (lane == 0) ? e0 : (lane == 1) ? e1 : (lane == 2) ? e2 : e3;
            sc[(size_t)(EE + n) * 4 + lane] = v;
        }
    }
    int beg = soff[n], end = soff[n + 1];
    for (int i = beg; i < end; i++) {
        int e = slist[i];
        int tail = ei[EE + e];
        int g = e >> 10;
        float h0 = 0, h1 = 0, h2 = 0, h3 = 0;
        #pragma unroll
        for (int j = 0; j < 4; j++) {
            int dd = lane + 64*j;
            if (dd < D) {
                float p = qv[j] * (XK[(size_t)tail*D + dd] + GK[g*D + dd]);
                int hh = dd / DH;
                if (hh == 0) h0 += p; else if (hh == 1) h1 += p; else if (hh == 2) h2 += p; else h3 += p;
            }
        }
        for (int o = 32; o; o >>= 1) {
            h0 += __shfl_xor(h0, o); h1 += __shfl_xor(h1, o);
            h2 += __shfl_xor(h2, o); h3 += __shfl_xor(h3, o);
        }
        float e0 = __expf(h0), e1 = __expf(h1), e2 = __expf(h2), e3 = __expf(h3);
        den0 += e0; den1 += e1; den2 += e2; den3 += e3;
        if (lane < 4) {
            float v = (lane == 0) ? e0 : (lane == 1) ? e1 : (lane == 2) ? e2 : e3;
            sc[(size_t)e * 4 + lane] = v;
        }
    }
    float cnt = (float)(outdeg[n] + 1);
    if (lane < 4) {
        float dn = (lane == 0) ? den0 : (lane == 1) ? den1 : (lane == 2) ? den2 : den3;
        scale[(size_t)n * 4 + lane] = cnt / dn;
    }
}

// ---------------- aggregation, dst-CSR, wave per node, no atomics ----------------
__global__ __launch_bounds__(256) void k_aggr(const int* __restrict__ ei, const int* __restrict__ nt,
                                              const int* __restrict__ doff, const int* __restrict__ dlist,
                                              const float* __restrict__ sc, const float* __restrict__ scale,
                                              const float* __restrict__ XM, const float* __restrict__ GM,
                                              const float* __restrict__ SM, float* __restrict__ aggr) {
    int wave = threadIdx.x >> 6, lane = threadIdx.x & 63;
    int n = blockIdx.x * 4 + wave;
    if (n >= NN) return;
    float acc[4] = {0.f, 0.f, 0.f, 0.f};
    // self message
    {
        int tn = nt[n];
        float4 ss = *(const float4*)&sc[(size_t)(EE + n) * 4];
        float4 sl = *(const float4*)&scale[(size_t)n * 4];
        float a0 = ss.x * sl.x, a1 = ss.y * sl.y, a2 = ss.z * sl.z, a3 = ss.w * sl.w;
        #pragma unroll
        for (int j = 0; j < 4; j++) {
            int dd = lane + 64*j;
            if (dd < D) {
                float al = (dd < DH) ? a0 : (dd < 2*DH) ? a1 : (dd < 3*DH) ? a2 : a3;
                acc[j] += al * (XM[(size_t)n*D + dd] + SM[tn*D + dd]);
            }
        }
    }
    int beg = doff[n], end = doff[n + 1];
    for (int i = beg; i < end; i++) {
        int e = dlist[i];
        int s = ei[e];
        int g = e >> 10;
        float4 ss = *(const float4*)&sc[(size_t)e * 4];
        float4 sl = *(const float4*)&scale[(size_t)s * 4];
        float a0 = ss.x * sl.x, a1 = ss.y * sl.y, a2 = ss.z * sl.z, a3 = ss.w * sl.w;
        #pragma unroll
        for (int j = 0; j < 4; j++) {
            int dd = lane + 64*j;
            if (dd < D) {
                float al = (dd < DH) ? a0 : (dd < 2*DH) ? a1 : (dd < 3*DH) ? a2 : a3;
                acc[j] += al * (XM[(size_t)s*D + dd] + GM[g*D + dd]);
            }
        }
    }
    #pragma unroll
    for (int j = 0; j < 4; j++) {
        int dd = lane + 64*j;
        if (dd < D) aggr[(size_t)n*D + dd] = acc[j];
    }
}

// ---------------- column stats for final BN ----------------
__global__ __launch_bounds__(256) void k_colstats(const float* __restrict__ T1, float* bn3) {
    int t = threadIdx.x;
    if (t >= D) return;
    int r0 = blockIdx.x * 256;
    float s = 0.f, q = 0.f;
    for (int r = r0; r < r0 + 256; r++) {
        float v = T1[(size_t)r * D + t];
        s += v; q += v * v;
    }
    unsafeAtomicAdd(&bn3[t], s);
    unsafeAtomicAdd(&bn3[D + t], q);
}

extern "C" void kernel_launch(void* const* d_in, const int* in_sizes, int n_in,
                              void* d_out, int out_size, void* d_ws, size_t ws_size,
                              hipStream_t stream) {
    const float* x    = (const float*)d_in[0];
    const float* sent = (const float*)d_in[2];
    const float* We1  = (const float*)d_in[3];
    const float* be1  = (const float*)d_in[4];
    const float* ge1  = (const float*)d_in[5];
    const float* bte1 = (const float*)d_in[6];
    const float* We2  = (const float*)d_in[7];
    const float* be2  = (const float*)d_in[8];
    const float* Wa1  = (const float*)d_in[9];
    const float* ba1  = (const float*)d_in[10];
    const float* ga1  = (const float*)d_in[11];
    const float* bta1 = (const float*)d_in[12];
    const float* Wa2  = (const float*)d_in[13];
    const float* ba2  = (const float*)d_in[14];
    const float* Watt = (const float*)d_in[15];
    const float* Wk   = (const float*)d_in[16];
    const float* bk   = (const float*)d_in[17];
    const float* Wm   = (const float*)d_in[18];
    const float* bm   = (const float*)d_in[19];
    const float* Wq   = (const float*)d_in[20];
    const float* bq   = (const float*)d_in[21];
    const float* Wo1  = (const float*)d_in[22];
    const float* bo1  = (const float*)d_in[23];
    const float* go1  = (const float*)d_in[24];
    const float* bto1 = (const float*)d_in[25];
    const float* Wo2  = (const float*)d_in[26];
    const float* bo2  = (const float*)d_in[27];
    const int* ei = (const int*)d_in[28];
    const int* et = (const int*)d_in[29];
    const int* nt = (const int*)d_in[30];

    char* ws = (char*)d_ws;
    size_t off = 0;
    auto alloc = [&](size_t bytes) -> char* {
        char* p = ws + off;
        off = (off + bytes + 255) & ~(size_t)255;
        return p;
    };
    // ---- zeroed region ----
    int*   hist   = (int*)  alloc(NC * 4);
    int*   ntcnt  = (int*)  alloc(NTY * 4);
    float* bn1    = (float*)alloc(2 * D * 4);
    float* bn2    = (float*)alloc(2 * D * 4);
    float* bn3    = (float*)alloc(2 * D * 4);
    float* sumsxf = (float*)alloc(NE * D * 4);
    int*   outdeg = (int*)  alloc(NN * 4);
    int*   indeg  = (int*)  alloc(NN * 4);
    size_t zero_end = off;
    // ---- rest ----
    int* tcnt = (int*)alloc(NE * 4);
    int* soff_ = (int*)alloc((NN + 1) * 4);
    int* doff_ = (int*)alloc((NN + 1) * 4);
    int* scur = (int*)alloc(NN * 4);
    int* dcur = (int*)alloc(NN * 4);
    int* slist = (int*)alloc((size_t)EE * 4);
    int* dlist = (int*)alloc((size_t)EE * 4);
    unsigned short* combo = (unsigned short*)alloc((size_t)EE * 2);
    float* h1v   = (float*)alloc((size_t)NCT * D * 4);
    float* embE  = (float*)alloc((size_t)NC * D * 4);
    float* embS  = (float*)alloc((size_t)NTY * D * 4);
    float* h2pre = (float*)alloc((size_t)NC * D * 4);
    float* Rc    = (float*)alloc((size_t)NC * D * 4);
    float* upd   = (float*)alloc((size_t)BG * D * 4);
    float* GK    = (float*)alloc((size_t)BG * D * 4);
    float* GM    = (float*)alloc((size_t)BG * D * 4);
    float* SK    = (float*)alloc((size_t)NTY * D * 4);
    float* SM    = (float*)alloc((size_t)NTY * D * 4);
    float* sc    = (float*)alloc((size_t)EA * H * 4);
    float* XK    = (float*)alloc((size_t)NN * D * 4);
    float* XM    = (float*)alloc((size_t)NN * D * 4);
    float* XQ    = (float*)alloc((size_t)NN * D * 4);
    // aliases (liveness-checked):
    float* coef  = XK;            // dead before k_mm3 writes XK
    float* scale = h1v;           // h1v+embE dead long before k_soft writes scale (needs 819KB < 976KB)
    float* aggr  = XQ;            // XQ dead after k_soft
    float* T1    = XK;            // XK dead after k_soft

    hipMemsetAsync(ws, 0, zero_end, stream);
    hipMemsetAsync(coef, 0, (size_t)NN * NE * 4, stream);

    k_hist   <<<EE / 256, 256, 0, stream>>>(ei, et, nt, hist, outdeg, indeg, combo);
    k_ntcnt  <<<NN / 256, 256, 0, stream>>>(nt, ntcnt);
    k_coef   <<<EE / 256, 256, 0, stream>>>(ei, et, coef);
    k_tcnt   <<<1, 64, 0, stream>>>(hist, tcnt);
    k_scan   <<<1, 256, 0, stream>>>(outdeg, indeg, soff_, doff_, scur, dcur);
    k_scatter<<<EE / 256, 256, 0, stream>>>(ei, scur, dcur, slist, dlist);
    k_xfsum3 <<<256, 256, 0, stream>>>(x, coef, sumsxf);
    k_combos1<<<NCT, 256, 0, stream>>>(We1, be1, hist, ntcnt, h1v, bn1);
    k_combos2<<<NCT, 256, 0, stream>>>(h1v, bn1, ge1, bte1, We2, be2, embE, embS);
    k_combos3<<<NC, 256, 0, stream>>>(embE, sumsxf, tcnt, Wa1, ba1, hist, h2pre, bn2);
    k_combos4<<<NC, 256, 0, stream>>>(h2pre, bn2, ga1, bta1, Wa2, ba2, Rc);
    k_attn   <<<BG, 256, 0, stream>>>(sent, Watt, Rc, combo, upd);
    k_gkgm   <<<BG + NTY, 256, 0, stream>>>(upd, embS, Wk, bk, Wm, bm, GK, GM, SK, SM);
    k_mm3    <<<NN / 64, 256, 0, stream>>>(x, Wk, Wm, Wq, bq, XK, XM, XQ);
    k_soft   <<<NN / 4, 256, 0, stream>>>(ei, nt, soff_, slist, outdeg, XQ, XK, GK, SK, sc, scale);
    k_aggr   <<<NN / 4, 256, 0, stream>>>(ei, nt, doff_, dlist, sc, scale, XM, GM, SM, aggr);
    k_mm200  <<<NN / 64, 256, 0, stream>>>(aggr, Wo1, bo1, T1, 0, nullptr, 0.f, nullptr, nullptr, 1.f);
    k_colstats<<<NN / 256, 256, 0, stream>>>(T1, bn3);
    k_mm200  <<<NN / 64, 256, 0, stream>>>(T1, Wo2, bo2, (float*)d_out, 1, bn3, 1.f / (float)NN, go1, bto1, 1.f);
}

// Round 4
// 1608.475 us; speedup vs baseline: 1.6855x; 1.1611x over previous
//
#include <hip/hip_runtime.h>

#define D     200
#define H     4
#define DH    50
#define NE    38
#define NTY   4
#define NC    608      // edge combos = 38*4*4
#define NCT   612      // + 4 self combos
#define BG    256      // graphs
#define LG    1024     // edges per graph
#define EE    262144   // E
#define NN    51200    // N
#define EA    313344   // E + N

#define NTILES 13      // ceil(200/16)
#define KSTEPS 7       // ceil(200/32)

typedef __attribute__((ext_vector_type(4))) float  f32x4;
typedef __attribute__((ext_vector_type(8))) short  bf16x8;

__device__ __forceinline__ short bf_hi(float f) {
    unsigned u = __float_as_uint(f);
    unsigned r = u + 0x7fffu + ((u >> 16) & 1u);
    return (short)(r >> 16);
}
__device__ __forceinline__ float bf_f(short s) {
    return __uint_as_float(((unsigned)(unsigned short)s) << 16);
}

// ---------------- histogram / combo / degrees ----------------
__global__ __launch_bounds__(256) void k_hist(const int* __restrict__ ei, const int* __restrict__ et,
                                              const int* __restrict__ nt, int* hist, int* outdeg, int* indeg,
                                              unsigned short* __restrict__ combo) {
    int e = blockIdx.x * 256 + threadIdx.x;
    if (e >= EE) return;
    int s = ei[e], d = ei[EE + e];
    int c = et[e] * 16 + nt[s] * 4 + nt[d];
    combo[e] = (unsigned short)c;
    atomicAdd(&hist[c], 1);
    atomicAdd(&outdeg[s], 1);
    atomicAdd(&indeg[d], 1);
}

__global__ __launch_bounds__(256) void k_ntcnt(const int* __restrict__ nt, int* ntcnt) {
    int n = blockIdx.x * 256 + threadIdx.x;
    if (n < NN) atomicAdd(&ntcnt[nt[n]], 1);
}

__global__ void k_tcnt(const int* __restrict__ hist, int* tcnt) {
    int t = threadIdx.x;
    if (t < NE) { int s = 0; for (int i = 0; i < 16; i++) s += hist[t*16 + i]; tcnt[t] = s; }
}

// ---------------- per-(node,type) signed coefficients ----------------
__global__ __launch_bounds__(256) void k_coef(const int* __restrict__ ei, const int* __restrict__ et,
                                              float* coef) {
    int e = blockIdx.x * 256 + threadIdx.x;
    if (e >= EE) return;
    int s = ei[e], d = ei[EE + e], t = et[e];
    unsafeAtomicAdd(&coef[(size_t)d * NE + t],  1.f);
    unsafeAtomicAdd(&coef[(size_t)s * NE + t], -1.f);
}

// sums = coef^T (38 x NN) @ x (NN x 200), K-split GEMM.
__global__ __launch_bounds__(256) void k_xfsum3(const float* __restrict__ x, const float* __restrict__ coef,
                                                float* sums) {
    const int CH = NN / 256;   // 200 nodes per block
    int t = threadIdx.x;
    int n0 = blockIdx.x * CH;
    float acc[NE];
    #pragma unroll
    for (int m = 0; m < NE; m++) acc[m] = 0.f;
    if (t < D) {
        for (int k = 0; k < CH; k++) {
            int n = n0 + k;
            float xv = x[(size_t)n * D + t];
            const float* cf = coef + (size_t)n * NE;
            #pragma unroll
            for (int m = 0; m < NE; m++) acc[m] += cf[m] * xv;
        }
        #pragma unroll
        for (int m = 0; m < NE; m++)
            if (acc[m] != 0.f) unsafeAtomicAdd(&sums[m * D + t], acc[m]);
    }
}

// ---------------- CSR build: scan + scatter ----------------
__global__ __launch_bounds__(256) void k_scan(const int* __restrict__ a, const int* __restrict__ b,
                                              int* aoff, int* boff, int* acur, int* bcur) {
    __shared__ int pa[256], pb[256];
    int t = threadIdx.x;
    const int CH = NN / 256;   // 200
    int base = t * CH;
    int s0 = 0, s1 = 0;
    for (int i = 0; i < CH; i++) { s0 += a[base + i]; s1 += b[base + i]; }
    pa[t] = s0; pb[t] = s1; __syncthreads();
    for (int off = 1; off < 256; off <<= 1) {
        int va = (t >= off) ? pa[t - off] : 0;
        int vb = (t >= off) ? pb[t - off] : 0;
        __syncthreads();
        pa[t] += va; pb[t] += vb;
        __syncthreads();
    }
    int ra = pa[t] - s0, rb = pb[t] - s1;
    for (int i = 0; i < CH; i++) {
        aoff[base + i] = ra; acur[base + i] = ra; ra += a[base + i];
        boff[base + i] = rb; bcur[base + i] = rb; rb += b[base + i];
    }
    if (t == 255) { aoff[NN] = ra; boff[NN] = rb; }
}

__global__ __launch_bounds__(256) void k_scatter(const int* __restrict__ ei, int* scur, int* dcur,
                                                 int* slist, int* dlist) {
    int e = blockIdx.x * 256 + threadIdx.x;
    if (e >= EE) return;
    int s = ei[e], d = ei[EE + e];
    slist[atomicAdd(&scur[s], 1)] = e;
    dlist[atomicAdd(&dcur[d], 1)] = e;
}

// ---------------- per-combo MLP pipeline ----------------
__global__ __launch_bounds__(256) void k_combos1(const float* __restrict__ We1, const float* __restrict__ be1,
                                                 const int* __restrict__ hist, const int* __restrict__ ntcnt,
                                                 float* __restrict__ h1, float* bn1) {
    int c = blockIdx.x, d = threadIdx.x;
    if (d >= D) return;
    float v, w;
    if (c < NC) {
        int etp = c >> 4, ts = (c >> 2) & 3, td = c & 3;
        v = We1[etp*D + d] + We1[(39+ts)*D + d] + We1[(43+td)*D + d] + be1[d];
        w = (float)hist[c];
    } else {
        int t = c - NC;
        v = We1[38*D + d] + We1[(39+t)*D + d] + We1[(43+t)*D + d] + be1[d];
        w = (float)ntcnt[t];
    }
    h1[c*D + d] = v;
    unsafeAtomicAdd(&bn1[d], w * v);
    unsafeAtomicAdd(&bn1[D + d], w * v * v);
}

__global__ __launch_bounds__(256) void k_combos2(const float* __restrict__ h1, const float* __restrict__ bn1,
                                                 const float* __restrict__ ge1, const float* __restrict__ bte1,
                                                 const float* __restrict__ We2, const float* __restrict__ be2,
                                                 float* __restrict__ embE, float* __restrict__ embS) {
    __shared__ float v[D];
    int c = blockIdx.x, t = threadIdx.x;
    if (t < D) {
        float cnt = (float)(EE + NN);
        float m = bn1[t] / cnt;
        float var = bn1[D + t] / cnt - m * m;
        float r = rsqrtf(var + 1e-5f);
        float u = (h1[c*D + t] - m) * r * ge1[t] + bte1[t];
        v[t] = fmaxf(u, 0.f);
    }
    __syncthreads();
    if (t < D) {
        float acc = be2[t];
        for (int k = 0; k < D; k++) acc += v[k] * We2[k*D + t];
        if (c < NC) embE[c*D + t] = acc; else embS[(c-NC)*D + t] = acc;
    }
}

__global__ __launch_bounds__(256) void k_combos3(const float* __restrict__ embE, const float* __restrict__ sumsxf,
                                                 const int* __restrict__ tcnt, const float* __restrict__ Wa1,
                                                 const float* __restrict__ ba1, const int* __restrict__ hist,
                                                 float* __restrict__ h2, float* bn2) {
    __shared__ float a[2*D];
    int c = blockIdx.x, t = threadIdx.x;
    int etp = c >> 4;
    if (t < D) {
        a[t] = embE[c*D + t];
        float cn = fmaxf((float)tcnt[etp], 1.f);
        a[D + t] = sumsxf[etp*D + t] / cn;
    }
    __syncthreads();
    if (t < D) {
        float acc = ba1[t];
        for (int k = 0; k < 2*D; k++) acc += a[k] * Wa1[k*D + t];
        h2[c*D + t] = acc;
        float w = (float)hist[c];
        unsafeAtomicAdd(&bn2[t], w * acc);
        unsafeAtomicAdd(&bn2[D + t], w * acc * acc);
    }
}

__global__ __launch_bounds__(256) void k_combos4(const float* __restrict__ h2, const float* __restrict__ bn2,
                                                 const float* __restrict__ ga1, const float* __restrict__ bta1,
                                                 const float* __restrict__ Wa2, const float* __restrict__ ba2,
                                                 float* __restrict__ Rc) {
    __shared__ float v[D];
    int c = blockIdx.x, t = threadIdx.x;
    if (t < D) {
        float inv = 1.f / (float)EE;
        float m = bn2[t] * inv;
        float var = bn2[D + t] * inv - m * m;
        float r = rsqrtf(var + 1e-5f);
        float u = (h2[c*D + t] - m) * r * ga1[t] + bta1[t];
        v[t] = fmaxf(u, 0.f);
    }
    __syncthreads();
    if (t < D) {
        float acc = ba2[t];
        for (int k = 0; k < D; k++) acc += v[k] * Wa2[k*D + t];
        Rc[c*D + t] = acc;
    }
}

// ---------------- per-graph attention over R ----------------
__global__ __launch_bounds__(256) void k_attn(const float* __restrict__ sent, const float* __restrict__ Watt,
                                              const float* __restrict__ Rc, const unsigned short* __restrict__ combo,
                                              float* __restrict__ upd) {
    __shared__ float q[D];
    __shared__ float sex[LG];
    __shared__ unsigned short cl[LG];
    __shared__ float red[8];
    __shared__ float part[4][D];
    int b = blockIdx.x, t = threadIdx.x;
    if (t < D) {
        float acc = 0.f;
        for (int k = 0; k < D; k++) acc += sent[b*D + k] * Watt[k*D + t];
        q[t] = acc;
    }
    for (int l = t; l < LG; l += 256) cl[l] = combo[b*LG + l];
    __syncthreads();
    int wave = t >> 6, lane = t & 63;
    const float scale = rsqrtf((float)D);
    for (int l = wave; l < LG; l += 4) {
        const float* r = Rc + cl[l] * D;
        float p = 0.f;
        for (int dd = lane; dd < D; dd += 64) p += q[dd] * r[dd];
        for (int o = 32; o; o >>= 1) p += __shfl_xor(p, o);
        if (lane == 0) sex[l] = p * scale;
    }
    __syncthreads();
    float mx = -1e30f;
    for (int l = t; l < LG; l += 256) mx = fmaxf(mx, sex[l]);
    for (int o = 32; o; o >>= 1) mx = fmaxf(mx, __shfl_xor(mx, o));
    if (lane == 0) red[wave] = mx;
    __syncthreads();
    mx = fmaxf(fmaxf(red[0], red[1]), fmaxf(red[2], red[3]));
    __syncthreads();
    float sm = 0.f;
    for (int l = t; l < LG; l += 256) { float e2 = __expf(sex[l] - mx); sex[l] = e2; sm += e2; }
    for (int o = 32; o; o >>= 1) sm += __shfl_xor(sm, o);
    if (lane == 0) red[4 + wave] = sm;
    __syncthreads();
    float inv = 1.f / (red[4] + red[5] + red[6] + red[7]);
    float acc[4] = {0.f, 0.f, 0.f, 0.f};
    for (int l = wave * 256; l < wave * 256 + 256; l++) {
        float s = sex[l];
        const float* r = Rc + cl[l] * D;
        #pragma unroll
        for (int j = 0; j < 4; j++) { int dd = lane + 64*j; if (dd < D) acc[j] += s * r[dd]; }
    }
    #pragma unroll
    for (int j = 0; j < 4; j++) { int dd = lane + 64*j; if (dd < D) part[wave][dd] = acc[j]; }
    __syncthreads();
    if (t < D) upd[b*D + t] = (part[0][t] + part[1][t] + part[2][t] + part[3][t]) * inv;
}

// ---------------- GK/GM (per graph) and SK/SM (per node type) ----------------
__global__ __launch_bounds__(256) void k_gkgm(const float* __restrict__ upd, const float* __restrict__ embS,
                                              const float* __restrict__ Wk, const float* __restrict__ bk,
                                              const float* __restrict__ Wm, const float* __restrict__ bm,
                                              float* GK, float* GM, float* SK, float* SM) {
    __shared__ float v[D];
    int bI = blockIdx.x, t = threadIdx.x;
    const float* in = (bI < BG) ? (upd + bI*D) : (embS + (bI - BG)*D);
    if (t < D) v[t] = in[t];
    __syncthreads();
    if (t < D) {
        float a1 = bk[t], a2 = bm[t];
        for (int k = 0; k < D; k++) {
            a1 += v[k] * Wk[(D + k)*D + t];
            a2 += v[k] * Wm[(D + k)*D + t];
        }
        if (bI < BG) { GK[bI*D + t] = a1; GM[bI*D + t] = a2; }
        else         { SK[(bI-BG)*D + t] = a1; SM[(bI-BG)*D + t] = a2; }
    }
}

// ---------------- weight packing: B-fragment order, bf16 hi/lo ----------------
// layout: [mat][nt][ks][split][lane][8] bf16;  B[k][n]: n=nt*16+(lane&15), k=ks*32+(lane>>4)*8+j
__global__ __launch_bounds__(256) void k_packW(const float* __restrict__ Wk, const float* __restrict__ Wm,
                                               const float* __restrict__ Wq, const float* __restrict__ Wo1,
                                               const float* __restrict__ Wo2, short* __restrict__ Bpk) {
    int blk = blockIdx.x;                    // mat*91 + nt*7 + ks
    int mat = blk / (NTILES * KSTEPS);
    int rem = blk - mat * (NTILES * KSTEPS);
    int nt = rem / KSTEPS, ks = rem - nt * KSTEPS;
    const float* W = (mat == 0) ? Wk : (mat == 1) ? Wm : (mat == 2) ? Wq : (mat == 3) ? Wo1 : Wo2;
    int t = threadIdx.x;
    for (int idx = t; idx < 1024; idx += 256) {
        int split = idx >> 9;
        int lane = (idx & 511) >> 3;
        int j = idx & 7;
        int n = nt * 16 + (lane & 15);
        int k = ks * 32 + ((lane >> 4) << 3) + j;
        float v = (k < D && n < D) ? W[k * D + n] : 0.f;
        short h = bf_hi(v);
        short out = split ? bf_hi(v - bf_f(h)) : h;
        Bpk[(size_t)blk * 1024 + idx] = out;
    }
}

// ---------------- MFMA GEMM core helpers ----------------
// A staged in LDS in A-fragment order: [strip 4][ks 7][split 2][lane 64][8] bf16 (57344 B)
__device__ __forceinline__ void stage_A(const float* __restrict__ A, int n0, short* Apk,
                                        int preop, const float* scl, const float* sft) {
    int t = threadIdx.x;
    bf16x8* Apk8 = (bf16x8*)Apk;
    for (int f = t; f < 64 * 28; f += 256) {
        int r = f / 28, g = f - 28 * r;
        float v[8];
        if (g < 25) {
            const float* src = A + (size_t)(n0 + r) * D + g * 8;
            float4 p0 = *(const float4*)src;
            float4 p1 = *(const float4*)(src + 4);
            v[0]=p0.x; v[1]=p0.y; v[2]=p0.z; v[3]=p0.w;
            v[4]=p1.x; v[5]=p1.y; v[6]=p1.z; v[7]=p1.w;
            if (preop) {
                #pragma unroll
                for (int j = 0; j < 8; j++) v[j] = fmaxf(v[j] * scl[g*8+j] + sft[g*8+j], 0.f);
            }
        } else {
            #pragma unroll
            for (int j = 0; j < 8; j++) v[j] = 0.f;
        }
        bf16x8 hi, lo;
        #pragma unroll
        for (int j = 0; j < 8; j++) {
            short h = bf_hi(v[j]);
            hi[j] = h;
            lo[j] = bf_hi(v[j] - bf_f(h));
        }
        int strip = r >> 4, lanem = r & 15, ks = g >> 2, quad = g & 3;
        int lane = lanem | (quad << 4);
        Apk8[((strip * KSTEPS + ks) * 2 + 0) * 64 + lane] = hi;
        Apk8[((strip * KSTEPS + ks) * 2 + 1) * 64 + lane] = lo;
    }
}

__device__ __forceinline__ void mfma_strip(const short* Apk, const short* Bmat, int w, int lane,
                                           f32x4 acc[NTILES]) {
    const bf16x8* Apk8 = (const bf16x8*)Apk;
    const bf16x8* B8   = (const bf16x8*)Bmat;
    #pragma unroll
    for (int nt = 0; nt < NTILES; nt++) { acc[nt][0]=0.f; acc[nt][1]=0.f; acc[nt][2]=0.f; acc[nt][3]=0.f; }
    for (int ks = 0; ks < KSTEPS; ks++) {
        bf16x8 ah = Apk8[((w * KSTEPS + ks) * 2 + 0) * 64 + lane];
        bf16x8 al = Apk8[((w * KSTEPS + ks) * 2 + 1) * 64 + lane];
        #pragma unroll
        for (int nt = 0; nt < NTILES; nt++) {
            bf16x8 bh = B8[((nt * KSTEPS + ks) * 2 + 0) * 64 + lane];
            bf16x8 bl = B8[((nt * KSTEPS + ks) * 2 + 1) * 64 + lane];
            acc[nt] = __builtin_amdgcn_mfma_f32_16x16x32_bf16(al, bh, acc[nt], 0, 0, 0);
            acc[nt] = __builtin_amdgcn_mfma_f32_16x16x32_bf16(ah, bl, acc[nt], 0, 0, 0);
            acc[nt] = __builtin_amdgcn_mfma_f32_16x16x32_bf16(ah, bh, acc[nt], 0, 0, 0);
        }
    }
}

__device__ __forceinline__ void store_C(f32x4 acc[NTILES], float* __restrict__ C, int n0, int w, int lane,
                                        const float* __restrict__ bias, float postscale) {
    int colb = lane & 15, quad = lane >> 4;
    #pragma unroll
    for (int nt = 0; nt < NTILES; nt++) {
        int col = nt * 16 + colb;
        if (col < D) {
            float bj = bias ? bias[col] : 0.f;
            #pragma unroll
            for (int r = 0; r < 4; r++) {
                int row = n0 + w * 16 + quad * 4 + r;
                C[(size_t)row * D + col] = (acc[nt][r] + bj) * postscale;
            }
        }
    }
}

// ---------------- fused x @ {Wk[:D], Wm[:D], Wq}  (MFMA) ----------------
__global__ __launch_bounds__(256) void k_mmf3(const float* __restrict__ A, const short* __restrict__ Bpk,
                                              const float* __restrict__ bq,
                                              float* __restrict__ XK, float* __restrict__ XM, float* __restrict__ XQ) {
    __shared__ short Apk[4 * KSTEPS * 2 * 64 * 8];
    int n0 = blockIdx.x * 64;
    stage_A(A, n0, Apk, 0, nullptr, nullptr);
    __syncthreads();
    int w = threadIdx.x >> 6, lane = threadIdx.x & 63;
    f32x4 acc[NTILES];
    const int matstride = NTILES * KSTEPS * 1024;   // shorts per mat = 91*1024
    // mat 0: XK
    mfma_strip(Apk, Bpk + 0 * matstride, w, lane, acc);
    store_C(acc, XK, n0, w, lane, nullptr, 1.f);
    // mat 1: XM
    mfma_strip(Apk, Bpk + 1 * matstride, w, lane, acc);
    store_C(acc, XM, n0, w, lane, nullptr, 1.f);
    // mat 2: XQ
    mfma_strip(Apk, Bpk + 2 * matstride, w, lane, acc);
    store_C(acc, XQ, n0, w, lane, bq, 0.14142135623730950488f);
}

// ---------------- generic MFMA matmul (one B), optional BN+relu preop ----------------
__global__ __launch_bounds__(256) void k_mmf(const float* __restrict__ A, const short* __restrict__ Bmat,
                                             const float* __restrict__ bias, float* __restrict__ C,
                                             int preop, const float* __restrict__ bnacc, float invCnt,
                                             const float* __restrict__ g, const float* __restrict__ bb,
                                             float postscale) {
    __shared__ short Apk[4 * KSTEPS * 2 * 64 * 8];
    __shared__ float scl[D], sft[D];
    int t = threadIdx.x;
    int n0 = blockIdx.x * 64;
    if (preop) {
        if (t < D) {
            float m = bnacc[t] * invCnt;
            float var = bnacc[D + t] * invCnt - m * m;
            float rs = rsqrtf(var + 1e-5f);
            float s = rs * g[t];
            scl[t] = s;
            sft[t] = bb[t] - m * s;
        }
        __syncthreads();
    }
    stage_A(A, n0, Apk, preop, scl, sft);
    __syncthreads();
    int w = t >> 6, lane = t & 63;
    f32x4 acc[NTILES];
    mfma_strip(Apk, Bmat, w, lane, acc);
    store_C(acc, C, n0, w, lane, bias, postscale);
}

// ---------------- edge softmax, src-CSR, wave per node, no atomics ----------------
__global__ __launch_bounds__(256) void k_soft(const int* __restrict__ ei, const int* __restrict__ nt,
                                              const int* __restrict__ soff, const int* __restrict__ slist,
                                              const int* __restrict__ outdeg,
                                              const float* __restrict__ XQ, const float* __restrict__ XK,
                                              const float* __restrict__ GK, const float* __restrict__ SK,
                                              float* __restrict__ sc, float* __restrict__ scale) {
    int wave = threadIdx.x >> 6, lane = threadIdx.x & 63;
    int n = blockIdx.x * 4 + wave;
    if (n >= NN) return;
    float qv[4];
    #pragma unroll
    for (int j = 0; j < 4; j++) { int dd = lane + 64*j; qv[j] = (dd < D) ? XQ[(size_t)n*D + dd] : 0.f; }
    float den0 = 0.f, den1 = 0.f, den2 = 0.f, den3 = 0.f;
    {
        int tn = nt[n];
        float h0 = 0, h1 = 0, h2 = 0, h3 = 0;
        #pragma unroll
        for (int j = 0; j < 4; j++) {
            int dd = lane + 64*j;
            if (dd < D) {
                float p = qv[j] * (XK[(size_t)n*D + dd] + SK[tn*D + dd]);
                int hh = dd / DH;
                if (hh == 0) h0 += p; else if (hh == 1) h1 += p; else if (hh == 2) h2 += p; else h3 += p;
            }
        }
        for (int o = 32; o; o >>= 1) {
            h0 += __shfl_xor(h0, o); h1 += __shfl_xor(h1, o);
            h2 += __shfl_xor(h2, o); h3 += __shfl_xor(h3, o);
        }
        float e0 = __expf(h0), e1 = __expf(h1), e2 = __expf(h2), e3 = __expf(h3);
        den0 += e0; den1 += e1; den2 += e2; den3 += e3;
        if (lane < 4) {
            float v = (lane == 0) ? e0 : (lane == 1) ? e1 : (lane == 2) ? e2 : e3;
            sc[(size_t)(EE + n) * 4 + lane] = v;
        }
    }
    int beg = soff[n], end = soff[n + 1];
    for (int i = beg; i < end; i++) {
        int e = slist[i];
        int tail = ei[EE + e];
        int g = e >> 10;
        float h0 = 0, h1 = 0, h2 = 0, h3 = 0;
        #pragma unroll
        for (int j = 0; j < 4; j++) {
            int dd = lane + 64*j;
            if (dd < D) {
                float p = qv[j] * (XK[(size_t)tail*D + dd] + GK[g*D + dd]);
                int hh = dd / DH;
                if (hh == 0) h0 += p; else if (hh == 1) h1 += p; else if (hh == 2) h2 += p; else h3 += p;
            }
        }
        for (int o = 32; o; o >>= 1) {
            h0 += __shfl_xor(h0, o); h1 += __shfl_xor(h1, o);
            h2 += __shfl_xor(h2, o); h3 += __shfl_xor(h3, o);
        }
        float e0 = __expf(h0), e1 = __expf(h1), e2 = __expf(h2), e3 = __expf(h3);
        den0 += e0; den1 += e1; den2 += e2; den3 += e3;
        if (lane < 4) {
            float v = (lane == 0) ? e0 : (lane == 1) ? e1 : (lane == 2) ? e2 : e3;
            sc[(size_t)e * 4 + lane] = v;
        }
    }
    float cnt = (float)(outdeg[n] + 1);
    if (lane < 4) {
        float dn = (lane == 0) ? den0 : (lane == 1) ? den1 : (lane == 2) ? den2 : den3;
        scale[(size_t)n * 4 + lane] = cnt / dn;
    }
}

// ---------------- aggregation, dst-CSR, wave per node, no atomics ----------------
__global__ __launch_bounds__(256) void k_aggr(const int* __restrict__ ei, const int* __restrict__ nt,
                                              const int* __restrict__ doff, const int* __restrict__ dlist,
                                              const float* __restrict__ sc, const float* __restrict__ scale,
                                              const float* __restrict__ XM, const float* __restrict__ GM,
                                              const float* __restrict__ SM, float* __restrict__ aggr) {
    int wave = threadIdx.x >> 6, lane = threadIdx.x & 63;
    int n = blockIdx.x * 4 + wave;
    if (n >= NN) return;
    float acc[4] = {0.f, 0.f, 0.f, 0.f};
    {
        int tn = nt[n];
        float4 ss = *(const float4*)&sc[(size_t)(EE + n) * 4];
        float4 sl = *(const float4*)&scale[(size_t)n * 4];
        float a0 = ss.x * sl.x, a1 = ss.y * sl.y, a2 = ss.z * sl.z, a3 = ss.w * sl.w;
        #pragma unroll
        for (int j = 0; j < 4; j++) {
            int dd = lane + 64*j;
            if (dd < D) {
                float al = (dd < DH) ? a0 : (dd < 2*DH) ? a1 : (dd < 3*DH) ? a2 : a3;
                acc[j] += al * (XM[(size_t)n*D + dd] + SM[tn*D + dd]);
            }
        }
    }
    int beg = doff[n], end = doff[n + 1];
    for (int i = beg; i < end; i++) {
        int e = dlist[i];
        int s = ei[e];
        int g = e >> 10;
        float4 ss = *(const float4*)&sc[(size_t)e * 4];
        float4 sl = *(const float4*)&scale[(size_t)s * 4];
        float a0 = ss.x * sl.x, a1 = ss.y * sl.y, a2 = ss.z * sl.z, a3 = ss.w * sl.w;
        #pragma unroll
        for (int j = 0; j < 4; j++) {
            int dd = lane + 64*j;
            if (dd < D) {
                float al = (dd < DH) ? a0 : (dd < 2*DH) ? a1 : (dd < 3*DH) ? a2 : a3;
                acc[j] += al * (XM[(size_t)s*D + dd] + GM[g*D + dd]);
            }
        }
    }
    #pragma unroll
    for (int j = 0; j < 4; j++) {
        int dd = lane + 64*j;
        if (dd < D) aggr[(size_t)n*D + dd] = acc[j];
    }
}

// ---------------- column stats for final BN ----------------
__global__ __launch_bounds__(256) void k_colstats(const float* __restrict__ T1, float* bn3) {
    int t = threadIdx.x;
    if (t >= D) return;
    int r0 = blockIdx.x * 256;
    float s = 0.f, q = 0.f;
    for (int r = r0; r < r0 + 256; r++) {
        float v = T1[(size_t)r * D + t];
        s += v; q += v * v;
    }
    unsafeAtomicAdd(&bn3[t], s);
    unsafeAtomicAdd(&bn3[D + t], q);
}

extern "C" void kernel_launch(void* const* d_in, const int* in_sizes, int n_in,
                              void* d_out, int out_size, void* d_ws, size_t ws_size,
                              hipStream_t stream) {
    const float* x    = (const float*)d_in[0];
    const float* sent = (const float*)d_in[2];
    const float* We1  = (const float*)d_in[3];
    const float* be1  = (const float*)d_in[4];
    const float* ge1  = (const float*)d_in[5];
    const float* bte1 = (const float*)d_in[6];
    const float* We2  = (const float*)d_in[7];
    const float* be2  = (const float*)d_in[8];
    const float* Wa1  = (const float*)d_in[9];
    const float* ba1  = (const float*)d_in[10];
    const float* ga1  = (const float*)d_in[11];
    const float* bta1 = (const float*)d_in[12];
    const float* Wa2  = (const float*)d_in[13];
    const float* ba2  = (const float*)d_in[14];
    const float* Watt = (const float*)d_in[15];
    const float* Wk   = (const float*)d_in[16];
    const float* bk   = (const float*)d_in[17];
    const float* Wm   = (const float*)d_in[18];
    const float* bm   = (const float*)d_in[19];
    const float* Wq   = (const float*)d_in[20];
    const float* bq   = (const float*)d_in[21];
    const float* Wo1  = (const float*)d_in[22];
    const float* bo1  = (const float*)d_in[23];
    const float* go1  = (const float*)d_in[24];
    const float* bto1 = (const float*)d_in[25];
    const float* Wo2  = (const float*)d_in[26];
    const float* bo2  = (const float*)d_in[27];
    const int* ei = (const int*)d_in[28];
    const int* et = (const int*)d_in[29];
    const int* nt = (const int*)d_in[30];

    char* ws = (char*)d_ws;
    size_t off = 0;
    auto alloc = [&](size_t bytes) -> char* {
        char* p = ws + off;
        off = (off + bytes + 255) & ~(size_t)255;
        return p;
    };
    // ---- zeroed region ----
    int*   hist   = (int*)  alloc(NC * 4);
    int*   ntcnt  = (int*)  alloc(NTY * 4);
    float* bn1    = (float*)alloc(2 * D * 4);
    float* bn2    = (float*)alloc(2 * D * 4);
    float* bn3    = (float*)alloc(2 * D * 4);
    float* sumsxf = (float*)alloc(NE * D * 4);
    int*   outdeg = (int*)  alloc(NN * 4);
    int*   indeg  = (int*)  alloc(NN * 4);
    size_t zero_end = off;
    // ---- rest ----
    int* tcnt = (int*)alloc(NE * 4);
    int* soff_ = (int*)alloc((NN + 1) * 4);
    int* doff_ = (int*)alloc((NN + 1) * 4);
    int* scur = (int*)alloc(NN * 4);
    int* dcur = (int*)alloc(NN * 4);
    int* slist = (int*)alloc((size_t)EE * 4);
    int* dlist = (int*)alloc((size_t)EE * 4);
    unsigned short* combo = (unsigned short*)alloc((size_t)EE * 2);
    short* Bpk  = (short*)alloc((size_t)5 * NTILES * KSTEPS * 1024 * 2);   // 5 mats, bf16 hi/lo packed
    float* h1v   = (float*)alloc((size_t)NCT * D * 4);
    float* embE  = (float*)alloc((size_t)NC * D * 4);
    float* embS  = (float*)alloc((size_t)NTY * D * 4);
    float* h2pre = (float*)alloc((size_t)NC * D * 4);
    float* Rc    = (float*)alloc((size_t)NC * D * 4);
    float* upd   = (float*)alloc((size_t)BG * D * 4);
    float* GK    = (float*)alloc((size_t)BG * D * 4);
    float* GM    = (float*)alloc((size_t)BG * D * 4);
    float* SK    = (float*)alloc((size_t)NTY * D * 4);
    float* SM    = (float*)alloc((size_t)NTY * D * 4);
    float* sc    = (float*)alloc((size_t)EA * H * 4);
    float* XK    = (float*)alloc((size_t)NN * D * 4);
    float* XM    = (float*)alloc((size_t)NN * D * 4);
    float* XQ    = (float*)alloc((size_t)NN * D * 4);
    // aliases (liveness-checked):
    float* coef  = XK;            // dead before k_mmf3 writes XK
    float* scale = h1v;           // h1v dead before k_soft writes scale
    float* aggr  = XQ;            // XQ dead after k_soft
    float* T1    = XK;            // XK dead after k_soft

    const int matstride = NTILES * KSTEPS * 1024;   // shorts per packed mat

    hipMemsetAsync(ws, 0, zero_end, stream);
    hipMemsetAsync(coef, 0, (size_t)NN * NE * 4, stream);

    k_packW  <<<5 * NTILES * KSTEPS, 256, 0, stream>>>(Wk, Wm, Wq, Wo1, Wo2, Bpk);
    k_hist   <<<EE / 256, 256, 0, stream>>>(ei, et, nt, hist, outdeg, indeg, combo);
    k_ntcnt  <<<NN / 256, 256, 0, stream>>>(nt, ntcnt);
    k_coef   <<<EE / 256, 256, 0, stream>>>(ei, et, coef);
    k_tcnt   <<<1, 64, 0, stream>>>(hist, tcnt);
    k_scan   <<<1, 256, 0, stream>>>(outdeg, indeg, soff_, doff_, scur, dcur);
    k_scatter<<<EE / 256, 256, 0, stream>>>(ei, scur, dcur, slist, dlist);
    k_xfsum3 <<<256, 256, 0, stream>>>(x, coef, sumsxf);
    k_combos1<<<NCT, 256, 0, stream>>>(We1, be1, hist, ntcnt, h1v, bn1);
    k_combos2<<<NCT, 256, 0, stream>>>(h1v, bn1, ge1, bte1, We2, be2, embE, embS);
    k_combos3<<<NC, 256, 0, stream>>>(embE, sumsxf, tcnt, Wa1, ba1, hist, h2pre, bn2);
    k_combos4<<<NC, 256, 0, stream>>>(h2pre, bn2, ga1, bta1, Wa2, ba2, Rc);
    k_attn   <<<BG, 256, 0, stream>>>(sent, Watt, Rc, combo, upd);
    k_gkgm   <<<BG + NTY, 256, 0, stream>>>(upd, embS, Wk, bk, Wm, bm, GK, GM, SK, SM);
    k_mmf3   <<<NN / 64, 256, 0, stream>>>(x, Bpk, bq, XK, XM, XQ);
    k_soft   <<<NN / 4, 256, 0, stream>>>(ei, nt, soff_, slist, outdeg, XQ, XK, GK, SK, sc, scale);
    k_aggr   <<<NN / 4, 256, 0, stream>>>(ei, nt, doff_, dlist, sc, scale, XM, GM, SM, aggr);
    k_mmf    <<<NN / 64, 256, 0, stream>>>(aggr, Bpk + (size_t)3 * matstride, bo1, T1,
                                           0, nullptr, 0.f, nullptr, nullptr, 1.f);
    k_colstats<<<NN / 256, 256, 0, stream>>>(T1, bn3);
    k_mmf    <<<NN / 64, 256, 0, stream>>>(T1, Bpk + (size_t)4 * matstride, bo2, (float*)d_out,
                                           1, bn3, 1.f / (float)NN, go1, bto1, 1.f);
}

// Round 5
// 1330.295 us; speedup vs baseline: 2.0380x; 1.2091x over previous
//
#include <hip/hip_runtime.h>

#define D     200
#define H     4
#define DH    50
#define NE    38
#define NTY   4
#define NC    608      // edge combos = 38*4*4
#define NCT   612      // + 4 self combos
#define BG    256      // graphs
#define LG    1024     // edges per graph
#define EE    262144   // E
#define NN    51200    // N
#define EA    313344   // E + N

#define NTILES 13      // ceil(200/16)
#define KSTEPS 7       // ceil(200/32)

typedef __attribute__((ext_vector_type(4))) float  f32x4;
typedef __attribute__((ext_vector_type(8))) short  bf16x8;

__device__ __forceinline__ short bf_hi(float f) {
    unsigned u = __float_as_uint(f);
    unsigned r = u + 0x7fffu + ((u >> 16) & 1u);
    return (short)(r >> 16);
}
__device__ __forceinline__ float bf_f(short s) {
    return __uint_as_float(((unsigned)(unsigned short)s) << 16);
}

// ---------------- histogram / combo / degrees ----------------
__global__ __launch_bounds__(256) void k_hist(const int* __restrict__ ei, const int* __restrict__ et,
                                              const int* __restrict__ nt, int* hist, int* outdeg, int* indeg,
                                              unsigned short* __restrict__ combo) {
    int e = blockIdx.x * 256 + threadIdx.x;
    if (e >= EE) return;
    int s = ei[e], d = ei[EE + e];
    int c = et[e] * 16 + nt[s] * 4 + nt[d];
    combo[e] = (unsigned short)c;
    atomicAdd(&hist[c], 1);
    atomicAdd(&outdeg[s], 1);
    atomicAdd(&indeg[d], 1);
}

// per-block LDS reduction -> 4 global atomics per block (was 51200 atomics on 4 addresses)
__global__ __launch_bounds__(256) void k_ntcnt(const int* __restrict__ nt, int* ntcnt) {
    __shared__ int loc[NTY];
    int t = threadIdx.x;
    if (t < NTY) loc[t] = 0;
    __syncthreads();
    int n = blockIdx.x * 256 + t;
    if (n < NN) atomicAdd(&loc[nt[n]], 1);
    __syncthreads();
    if (t < NTY) atomicAdd(&ntcnt[t], loc[t]);
}

__global__ void k_tcnt(const int* __restrict__ hist, int* tcnt) {
    int t = threadIdx.x;
    if (t < NE) { int s = 0; for (int i = 0; i < 16; i++) s += hist[t*16 + i]; tcnt[t] = s; }
}

// ---------------- per-(node,type) signed coefficients ----------------
__global__ __launch_bounds__(256) void k_coef(const int* __restrict__ ei, const int* __restrict__ et,
                                              float* coef) {
    int e = blockIdx.x * 256 + threadIdx.x;
    if (e >= EE) return;
    int s = ei[e], d = ei[EE + e], t = et[e];
    unsafeAtomicAdd(&coef[(size_t)d * NE + t],  1.f);
    unsafeAtomicAdd(&coef[(size_t)s * NE + t], -1.f);
}

// sums = coef^T (38 x NN) @ x (NN x 200), K-split GEMM.
__global__ __launch_bounds__(256) void k_xfsum3(const float* __restrict__ x, const float* __restrict__ coef,
                                                float* sums) {
    const int CH = NN / 256;   // 200 nodes per block
    int t = threadIdx.x;
    int n0 = blockIdx.x * CH;
    float acc[NE];
    #pragma unroll
    for (int m = 0; m < NE; m++) acc[m] = 0.f;
    if (t < D) {
        for (int k = 0; k < CH; k++) {
            int n = n0 + k;
            float xv = x[(size_t)n * D + t];
            const float* cf = coef + (size_t)n * NE;
            #pragma unroll
            for (int m = 0; m < NE; m++) acc[m] += cf[m] * xv;
        }
        #pragma unroll
        for (int m = 0; m < NE; m++)
            if (acc[m] != 0.f) unsafeAtomicAdd(&sums[m * D + t], acc[m]);
    }
}

// ---------------- CSR build: scan + scatter ----------------
__global__ __launch_bounds__(256) void k_scan(const int* __restrict__ a, const int* __restrict__ b,
                                              int* aoff, int* boff, int* acur, int* bcur) {
    __shared__ int pa[256], pb[256];
    int t = threadIdx.x;
    const int CH = NN / 256;   // 200
    int base = t * CH;
    int s0 = 0, s1 = 0;
    for (int i = 0; i < CH; i++) { s0 += a[base + i]; s1 += b[base + i]; }
    pa[t] = s0; pb[t] = s1; __syncthreads();
    for (int off = 1; off < 256; off <<= 1) {
        int va = (t >= off) ? pa[t - off] : 0;
        int vb = (t >= off) ? pb[t - off] : 0;
        __syncthreads();
        pa[t] += va; pb[t] += vb;
        __syncthreads();
    }
    int ra = pa[t] - s0, rb = pb[t] - s1;
    for (int i = 0; i < CH; i++) {
        aoff[base + i] = ra; acur[base + i] = ra; ra += a[base + i];
        boff[base + i] = rb; bcur[base + i] = rb; rb += b[base + i];
    }
    if (t == 255) { aoff[NN] = ra; boff[NN] = rb; }
}

__global__ __launch_bounds__(256) void k_scatter(const int* __restrict__ ei, int* scur, int* dcur,
                                                 int* slist, int* dlist) {
    int e = blockIdx.x * 256 + threadIdx.x;
    if (e >= EE) return;
    int s = ei[e], d = ei[EE + e];
    slist[atomicAdd(&scur[s], 1)] = e;
    dlist[atomicAdd(&dcur[d], 1)] = e;
}

// ---------------- per-combo MLP pipeline ----------------
__global__ __launch_bounds__(256) void k_combos1(const float* __restrict__ We1, const float* __restrict__ be1,
                                                 const int* __restrict__ hist, const int* __restrict__ ntcnt,
                                                 float* __restrict__ h1, float* bn1) {
    int c = blockIdx.x, d = threadIdx.x;
    if (d >= D) return;
    float v, w;
    if (c < NC) {
        int etp = c >> 4, ts = (c >> 2) & 3, td = c & 3;
        v = We1[etp*D + d] + We1[(39+ts)*D + d] + We1[(43+td)*D + d] + be1[d];
        w = (float)hist[c];
    } else {
        int t = c - NC;
        v = We1[38*D + d] + We1[(39+t)*D + d] + We1[(43+t)*D + d] + be1[d];
        w = (float)ntcnt[t];
    }
    h1[c*D + d] = v;
    unsafeAtomicAdd(&bn1[d], w * v);
    unsafeAtomicAdd(&bn1[D + d], w * v * v);
}

__global__ __launch_bounds__(256) void k_combos2(const float* __restrict__ h1, const float* __restrict__ bn1,
                                                 const float* __restrict__ ge1, const float* __restrict__ bte1,
                                                 const float* __restrict__ We2, const float* __restrict__ be2,
                                                 float* __restrict__ embE, float* __restrict__ embS) {
    __shared__ float v[D];
    int c = blockIdx.x, t = threadIdx.x;
    if (t < D) {
        float cnt = (float)(EE + NN);
        float m = bn1[t] / cnt;
        float var = bn1[D + t] / cnt - m * m;
        float r = rsqrtf(var + 1e-5f);
        float u = (h1[c*D + t] - m) * r * ge1[t] + bte1[t];
        v[t] = fmaxf(u, 0.f);
    }
    __syncthreads();
    if (t < D) {
        float acc = be2[t];
        for (int k = 0; k < D; k++) acc += v[k] * We2[k*D + t];
        if (c < NC) embE[c*D + t] = acc; else embS[(c-NC)*D + t] = acc;
    }
}

__global__ __launch_bounds__(256) void k_combos3(const float* __restrict__ embE, const float* __restrict__ sumsxf,
                                                 const int* __restrict__ tcnt, const float* __restrict__ Wa1,
                                                 const float* __restrict__ ba1, const int* __restrict__ hist,
                                                 float* __restrict__ h2, float* bn2) {
    __shared__ float a[2*D];
    int c = blockIdx.x, t = threadIdx.x;
    int etp = c >> 4;
    if (t < D) {
        a[t] = embE[c*D + t];
        float cn = fmaxf((float)tcnt[etp], 1.f);
        a[D + t] = sumsxf[etp*D + t] / cn;
    }
    __syncthreads();
    if (t < D) {
        float acc = ba1[t];
        for (int k = 0; k < 2*D; k++) acc += a[k] * Wa1[k*D + t];
        h2[c*D + t] = acc;
        float w = (float)hist[c];
        unsafeAtomicAdd(&bn2[t], w * acc);
        unsafeAtomicAdd(&bn2[D + t], w * acc * acc);
    }
}

__global__ __launch_bounds__(256) void k_combos4(const float* __restrict__ h2, const float* __restrict__ bn2,
                                                 const float* __restrict__ ga1, const float* __restrict__ bta1,
                                                 const float* __restrict__ Wa2, const float* __restrict__ ba2,
                                                 float* __restrict__ Rc) {
    __shared__ float v[D];
    int c = blockIdx.x, t = threadIdx.x;
    if (t < D) {
        float inv = 1.f / (float)EE;
        float m = bn2[t] * inv;
        float var = bn2[D + t] * inv - m * m;
        float r = rsqrtf(var + 1e-5f);
        float u = (h2[c*D + t] - m) * r * ga1[t] + bta1[t];
        v[t] = fmaxf(u, 0.f);
    }
    __syncthreads();
    if (t < D) {
        float acc = ba2[t];
        for (int k = 0; k < D; k++) acc += v[k] * Wa2[k*D + t];
        Rc[c*D + t] = acc;
    }
}

// ---------------- per-graph attention over R ----------------
__global__ __launch_bounds__(256) void k_attn(const float* __restrict__ sent, const float* __restrict__ Watt,
                                              const float* __restrict__ Rc, const unsigned short* __restrict__ combo,
                                              float* __restrict__ upd) {
    __shared__ float q[D];
    __shared__ float sex[LG];
    __shared__ unsigned short cl[LG];
    __shared__ float red[8];
    __shared__ float part[4][D];
    int b = blockIdx.x, t = threadIdx.x;
    if (t < D) {
        float acc = 0.f;
        for (int k = 0; k < D; k++) acc += sent[b*D + k] * Watt[k*D + t];
        q[t] = acc;
    }
    for (int l = t; l < LG; l += 256) cl[l] = combo[b*LG + l];
    __syncthreads();
    int wave = t >> 6, lane = t & 63;
    const float scale = rsqrtf((float)D);
    for (int l = wave; l < LG; l += 4) {
        const float* r = Rc + cl[l] * D;
        float p = 0.f;
        for (int dd = lane; dd < D; dd += 64) p += q[dd] * r[dd];
        for (int o = 32; o; o >>= 1) p += __shfl_xor(p, o);
        if (lane == 0) sex[l] = p * scale;
    }
    __syncthreads();
    float mx = -1e30f;
    for (int l = t; l < LG; l += 256) mx = fmaxf(mx, sex[l]);
    for (int o = 32; o; o >>= 1) mx = fmaxf(mx, __shfl_xor(mx, o));
    if (lane == 0) red[wave] = mx;
    __syncthreads();
    mx = fmaxf(fmaxf(red[0], red[1]), fmaxf(red[2], red[3]));
    __syncthreads();
    float sm = 0.f;
    for (int l = t; l < LG; l += 256) { float e2 = __expf(sex[l] - mx); sex[l] = e2; sm += e2; }
    for (int o = 32; o; o >>= 1) sm += __shfl_xor(sm, o);
    if (lane == 0) red[4 + wave] = sm;
    __syncthreads();
    float inv = 1.f / (red[4] + red[5] + red[6] + red[7]);
    float acc[4] = {0.f, 0.f, 0.f, 0.f};
    for (int l = wave * 256; l < wave * 256 + 256; l++) {
        float s = sex[l];
        const float* r = Rc + cl[l] * D;
        #pragma unroll
        for (int j = 0; j < 4; j++) { int dd = lane + 64*j; if (dd < D) acc[j] += s * r[dd]; }
    }
    #pragma unroll
    for (int j = 0; j < 4; j++) { int dd = lane + 64*j; if (dd < D) part[wave][dd] = acc[j]; }
    __syncthreads();
    if (t < D) upd[b*D + t] = (part[0][t] + part[1][t] + part[2][t] + part[3][t]) * inv;
}

// ---------------- GK/GM (per graph) and SK/SM (per node type) ----------------
__global__ __launch_bounds__(256) void k_gkgm(const float* __restrict__ upd, const float* __restrict__ embS,
                                              const float* __restrict__ Wk, const float* __restrict__ bk,
                                              const float* __restrict__ Wm, const float* __restrict__ bm,
                                              float* GK, float* GM, float* SK, float* SM) {
    __shared__ float v[D];
    int bI = blockIdx.x, t = threadIdx.x;
    const float* in = (bI < BG) ? (upd + bI*D) : (embS + (bI - BG)*D);
    if (t < D) v[t] = in[t];
    __syncthreads();
    if (t < D) {
        float a1 = bk[t], a2 = bm[t];
        for (int k = 0; k < D; k++) {
            a1 += v[k] * Wk[(D + k)*D + t];
            a2 += v[k] * Wm[(D + k)*D + t];
        }
        if (bI < BG) { GK[bI*D + t] = a1; GM[bI*D + t] = a2; }
        else         { SK[(bI-BG)*D + t] = a1; SM[(bI-BG)*D + t] = a2; }
    }
}

// ---------------- weight packing: B-fragment order, bf16 hi/lo ----------------
__global__ __launch_bounds__(256) void k_packW(const float* __restrict__ Wk, const float* __restrict__ Wm,
                                               const float* __restrict__ Wq, const float* __restrict__ Wo1,
                                               const float* __restrict__ Wo2, short* __restrict__ Bpk) {
    int blk = blockIdx.x;                    // mat*91 + nt*7 + ks
    int mat = blk / (NTILES * KSTEPS);
    int rem = blk - mat * (NTILES * KSTEPS);
    int nt = rem / KSTEPS, ks = rem - nt * KSTEPS;
    const float* W = (mat == 0) ? Wk : (mat == 1) ? Wm : (mat == 2) ? Wq : (mat == 3) ? Wo1 : Wo2;
    int t = threadIdx.x;
    for (int idx = t; idx < 1024; idx += 256) {
        int split = idx >> 9;
        int lane = (idx & 511) >> 3;
        int j = idx & 7;
        int n = nt * 16 + (lane & 15);
        int k = ks * 32 + ((lane >> 4) << 3) + j;
        float v = (k < D && n < D) ? W[k * D + n] : 0.f;
        short h = bf_hi(v);
        short out = split ? bf_hi(v - bf_f(h)) : h;
        Bpk[(size_t)blk * 1024 + idx] = out;
    }
}

// ---------------- MFMA GEMM core helpers ----------------
__device__ __forceinline__ void stage_A(const float* __restrict__ A, int n0, short* Apk,
                                        int preop, const float* scl, const float* sft) {
    int t = threadIdx.x;
    bf16x8* Apk8 = (bf16x8*)Apk;
    for (int f = t; f < 64 * 28; f += 256) {
        int r = f / 28, g = f - 28 * r;
        float v[8];
        if (g < 25) {
            const float* src = A + (size_t)(n0 + r) * D + g * 8;
            float4 p0 = *(const float4*)src;
            float4 p1 = *(const float4*)(src + 4);
            v[0]=p0.x; v[1]=p0.y; v[2]=p0.z; v[3]=p0.w;
            v[4]=p1.x; v[5]=p1.y; v[6]=p1.z; v[7]=p1.w;
            if (preop) {
                #pragma unroll
                for (int j = 0; j < 8; j++) v[j] = fmaxf(v[j] * scl[g*8+j] + sft[g*8+j], 0.f);
            }
        } else {
            #pragma unroll
            for (int j = 0; j < 8; j++) v[j] = 0.f;
        }
        bf16x8 hi, lo;
        #pragma unroll
        for (int j = 0; j < 8; j++) {
            short h = bf_hi(v[j]);
            hi[j] = h;
            lo[j] = bf_hi(v[j] - bf_f(h));
        }
        int strip = r >> 4, lanem = r & 15, ks = g >> 2, quad = g & 3;
        int lane = lanem | (quad << 4);
        Apk8[((strip * KSTEPS + ks) * 2 + 0) * 64 + lane] = hi;
        Apk8[((strip * KSTEPS + ks) * 2 + 1) * 64 + lane] = lo;
    }
}

__device__ __forceinline__ void mfma_strip(const short* Apk, const short* Bmat, int w, int lane,
                                           f32x4 acc[NTILES]) {
    const bf16x8* Apk8 = (const bf16x8*)Apk;
    const bf16x8* B8   = (const bf16x8*)Bmat;
    #pragma unroll
    for (int nt = 0; nt < NTILES; nt++) { acc[nt][0]=0.f; acc[nt][1]=0.f; acc[nt][2]=0.f; acc[nt][3]=0.f; }
    for (int ks = 0; ks < KSTEPS; ks++) {
        bf16x8 ah = Apk8[((w * KSTEPS + ks) * 2 + 0) * 64 + lane];
        bf16x8 al = Apk8[((w * KSTEPS + ks) * 2 + 1) * 64 + lane];
        #pragma unroll
        for (int nt = 0; nt < NTILES; nt++) {
            bf16x8 bh = B8[((nt * KSTEPS + ks) * 2 + 0) * 64 + lane];
            bf16x8 bl = B8[((nt * KSTEPS + ks) * 2 + 1) * 64 + lane];
            acc[nt] = __builtin_amdgcn_mfma_f32_16x16x32_bf16(al, bh, acc[nt], 0, 0, 0);
            acc[nt] = __builtin_amdgcn_mfma_f32_16x16x32_bf16(ah, bl, acc[nt], 0, 0, 0);
            acc[nt] = __builtin_amdgcn_mfma_f32_16x16x32_bf16(ah, bh, acc[nt], 0, 0, 0);
        }
    }
}

__device__ __forceinline__ void store_C(f32x4 acc[NTILES], float* __restrict__ C, int n0, int w, int lane,
                                        const float* __restrict__ bias, float postscale) {
    int colb = lane & 15, quad = lane >> 4;
    #pragma unroll
    for (int nt = 0; nt < NTILES; nt++) {
        int col = nt * 16 + colb;
        if (col < D) {
            float bj = bias ? bias[col] : 0.f;
            #pragma unroll
            for (int r = 0; r < 4; r++) {
                int row = n0 + w * 16 + quad * 4 + r;
                C[(size_t)row * D + col] = (acc[nt][r] + bj) * postscale;
            }
        }
    }
}

// ---------------- fused x @ {Wk[:D], Wm[:D], Wq}  (MFMA) ----------------
__global__ __launch_bounds__(256) void k_mmf3(const float* __restrict__ A, const short* __restrict__ Bpk,
                                              const float* __restrict__ bq,
                                              float* __restrict__ XK, float* __restrict__ XM, float* __restrict__ XQ) {
    __shared__ short Apk[4 * KSTEPS * 2 * 64 * 8];
    int n0 = blockIdx.x * 64;
    stage_A(A, n0, Apk, 0, nullptr, nullptr);
    __syncthreads();
    int w = threadIdx.x >> 6, lane = threadIdx.x & 63;
    f32x4 acc[NTILES];
    const int matstride = NTILES * KSTEPS * 1024;   // shorts per mat = 91*1024
    mfma_strip(Apk, Bpk + 0 * matstride, w, lane, acc);
    store_C(acc, XK, n0, w, lane, nullptr, 1.f);
    mfma_strip(Apk, Bpk + 1 * matstride, w, lane, acc);
    store_C(acc, XM, n0, w, lane, nullptr, 1.f);
    mfma_strip(Apk, Bpk + 2 * matstride, w, lane, acc);
    store_C(acc, XQ, n0, w, lane, bq, 0.14142135623730950488f);
}

// ---------------- generic MFMA matmul (one B), optional BN+relu preop ----------------
__global__ __launch_bounds__(256) void k_mmf(const float* __restrict__ A, const short* __restrict__ Bmat,
                                             const float* __restrict__ bias, float* __restrict__ C,
                                             int preop, const float* __restrict__ bnacc, float invCnt,
                                             const float* __restrict__ g, const float* __restrict__ bb,
                                             float postscale) {
    __shared__ short Apk[4 * KSTEPS * 2 * 64 * 8];
    __shared__ float scl[D], sft[D];
    int t = threadIdx.x;
    int n0 = blockIdx.x * 64;
    if (preop) {
        if (t < D) {
            float m = bnacc[t] * invCnt;
            float var = bnacc[D + t] * invCnt - m * m;
            float rs = rsqrtf(var + 1e-5f);
            float s = rs * g[t];
            scl[t] = s;
            sft[t] = bb[t] - m * s;
        }
        __syncthreads();
    }
    stage_A(A, n0, Apk, preop, scl, sft);
    __syncthreads();
    int w = t >> 6, lane = t & 63;
    f32x4 acc[NTILES];
    mfma_strip(Apk, Bmat, w, lane, acc);
    store_C(acc, C, n0, w, lane, bias, postscale);
}

// ---------------- edge softmax, src-CSR, wave per node, no atomics ----------------
__global__ __launch_bounds__(256) void k_soft(const int* __restrict__ ei, const int* __restrict__ nt,
                                              const int* __restrict__ soff, const int* __restrict__ slist,
                                              const int* __restrict__ outdeg,
                                              const float* __restrict__ XQ, const float* __restrict__ XK,
                                              const float* __restrict__ GK, const float* __restrict__ SK,
                                              float* __restrict__ sc, float* __restrict__ scale) {
    int wave = threadIdx.x >> 6, lane = threadIdx.x & 63;
    int n = blockIdx.x * 4 + wave;
    if (n >= NN) return;
    float qv[4];
    #pragma unroll
    for (int j = 0; j < 4; j++) { int dd = lane + 64*j; qv[j] = (dd < D) ? XQ[(size_t)n*D + dd] : 0.f; }
    float den0 = 0.f, den1 = 0.f, den2 = 0.f, den3 = 0.f;
    {
        int tn = nt[n];
        float h0 = 0, h1 = 0, h2 = 0, h3 = 0;
        #pragma unroll
        for (int j = 0; j < 4; j++) {
            int dd = lane + 64*j;
            if (dd < D) {
                float p = qv[j] * (XK[(size_t)n*D + dd] + SK[tn*D + dd]);
                int hh = dd / DH;
                if (hh == 0) h0 += p; else if (hh == 1) h1 += p; else if (hh == 2) h2 += p; else h3 += p;
            }
        }
        for (int o = 32; o; o >>= 1) {
            h0 += __shfl_xor(h0, o); h1 += __shfl_xor(h1, o);
            h2 += __shfl_xor(h2, o); h3 += __shfl_xor(h3, o);
        }
        float e0 = __expf(h0), e1 = __expf(h1), e2 = __expf(h2), e3 = __expf(h3);
        den0 += e0; den1 += e1; den2 += e2; den3 += e3;
        if (lane < 4) {
            float v = (lane == 0) ? e0 : (lane == 1) ? e1 : (lane == 2) ? e2 : e3;
            sc[(size_t)(EE + n) * 4 + lane] = v;
        }
    }
    int beg = soff[n], end = soff[n + 1];
    for (int i = beg; i < end; i++) {
        int e = slist[i];
        int tail = ei[EE + e];
        int g = e >> 10;
        float h0 = 0, h1 = 0, h2 = 0, h3 = 0;
        #pragma unroll
        for (int j = 0; j < 4; j++) {
            int dd = lane + 64*j;
            if (dd < D) {
                float p = qv[j] * (XK[(size_t)tail*D + dd] + GK[g*D + dd]);
                int hh = dd / DH;
                if (hh == 0) h0 += p; else if (hh == 1) h1 += p; else if (hh == 2) h2 += p; else h3 += p;
            }
        }
        for (int o = 32; o; o >>= 1) {
            h0 += __shfl_xor(h0, o); h1 += __shfl_xor(h1, o);
            h2 += __shfl_xor(h2, o); h3 += __shfl_xor(h3, o);
        }
        float e0 = __expf(h0), e1 = __expf(h1), e2 = __expf(h2), e3 = __expf(h3);
        den0 += e0; den1 += e1; den2 += e2; den3 += e3;
        if (lane < 4) {
            float v = (lane == 0) ? e0 : (lane == 1) ? e1 : (lane == 2) ? e2 : e3;
            sc[(size_t)e * 4 + lane] = v;
        }
    }
    float cnt = (float)(outdeg[n] + 1);
    if (lane < 4) {
        float dn = (lane == 0) ? den0 : (lane == 1) ? den1 : (lane == 2) ? den2 : den3;
        scale[(size_t)n * 4 + lane] = cnt / dn;
    }
}

// ---------------- aggregation, dst-CSR, wave per node, no atomics ----------------
__global__ __launch_bounds__(256) void k_aggr(const int* __restrict__ ei, const int* __restrict__ nt,
                                              const int* __restrict__ doff, const int* __restrict__ dlist,
                                              const float* __restrict__ sc, const float* __restrict__ scale,
                                              const float* __restrict__ XM, const float* __restrict__ GM,
                                              const float* __restrict__ SM, float* __restrict__ aggr) {
    int wave = threadIdx.x >> 6, lane = threadIdx.x & 63;
    int n = blockIdx.x * 4 + wave;
    if (n >= NN) return;
    float acc[4] = {0.f, 0.f, 0.f, 0.f};
    {
        int tn = nt[n];
        float4 ss = *(const float4*)&sc[(size_t)(EE + n) * 4];
        float4 sl = *(const float4*)&scale[(size_t)n * 4];
        float a0 = ss.x * sl.x, a1 = ss.y * sl.y, a2 = ss.z * sl.z, a3 = ss.w * sl.w;
        #pragma unroll
        for (int j = 0; j < 4; j++) {
            int dd = lane + 64*j;
            if (dd < D) {
                float al = (dd < DH) ? a0 : (dd < 2*DH) ? a1 : (dd < 3*DH) ? a2 : a3;
                acc[j] += al * (XM[(size_t)n*D + dd] + SM[tn*D + dd]);
            }
        }
    }
    int beg = doff[n], end = doff[n + 1];
    for (int i = beg; i < end; i++) {
        int e = dlist[i];
        int s = ei[e];
        int g = e >> 10;
        float4 ss = *(const float4*)&sc[(size_t)e * 4];
        float4 sl = *(const float4*)&scale[(size_t)s * 4];
        float a0 = ss.x * sl.x, a1 = ss.y * sl.y, a2 = ss.z * sl.z, a3 = ss.w * sl.w;
        #pragma unroll
        for (int j = 0; j < 4; j++) {
            int dd = lane + 64*j;
            if (dd < D) {
                float al = (dd < DH) ? a0 : (dd < 2*DH) ? a1 : (dd < 3*DH) ? a2 : a3;
                acc[j] += al * (XM[(size_t)s*D + dd] + GM[g*D + dd]);
            }
        }
    }
    #pragma unroll
    for (int j = 0; j < 4; j++) {
        int dd = lane + 64*j;
        if (dd < D) aggr[(size_t)n*D + dd] = acc[j];
    }
}

// ---------------- column stats for final BN ----------------
__global__ __launch_bounds__(256) void k_colstats(const float* __restrict__ T1, float* bn3) {
    int t = threadIdx.x;
    if (t >= D) return;
    int r0 = blockIdx.x * 256;
    float s = 0.f, q = 0.f;
    for (int r = r0; r < r0 + 256; r++) {
        float v = T1[(size_t)r * D + t];
        s += v; q += v * v;
    }
    unsafeAtomicAdd(&bn3[t], s);
    unsafeAtomicAdd(&bn3[D + t], q);
}

extern "C" void kernel_launch(void* const* d_in, const int* in_sizes, int n_in,
                              void* d_out, int out_size, void* d_ws, size_t ws_size,
                              hipStream_t stream) {
    const float* x    = (const float*)d_in[0];
    const float* sent = (const float*)d_in[2];
    const float* We1  = (const float*)d_in[3];
    const float* be1  = (const float*)d_in[4];
    const float* ge1  = (const float*)d_in[5];
    const float* bte1 = (const float*)d_in[6];
    const float* We2  = (const float*)d_in[7];
    const float* be2  = (const float*)d_in[8];
    const float* Wa1  = (const float*)d_in[9];
    const float* ba1  = (const float*)d_in[10];
    const float* ga1  = (const float*)d_in[11];
    const float* bta1 = (const float*)d_in[12];
    const float* Wa2  = (const float*)d_in[13];
    const float* ba2  = (const float*)d_in[14];
    const float* Watt = (const float*)d_in[15];
    const float* Wk   = (const float*)d_in[16];
    const float* bk   = (const float*)d_in[17];
    const float* Wm   = (const float*)d_in[18];
    const float* bm   = (const float*)d_in[19];
    const float* Wq   = (const float*)d_in[20];
    const float* bq   = (const float*)d_in[21];
    const float* Wo1  = (const float*)d_in[22];
    const float* bo1  = (const float*)d_in[23];
    const float* go1  = (const float*)d_in[24];
    const float* bto1 = (const float*)d_in[25];
    const float* Wo2  = (const float*)d_in[26];
    const float* bo2  = (const float*)d_in[27];
    const int* ei = (const int*)d_in[28];
    const int* et = (const int*)d_in[29];
    const int* nt = (const int*)d_in[30];

    char* ws = (char*)d_ws;
    size_t off = 0;
    auto alloc = [&](size_t bytes) -> char* {
        char* p = ws + off;
        off = (off + bytes + 255) & ~(size_t)255;
        return p;
    };
    // ---- zeroed region ----
    int*   hist   = (int*)  alloc(NC * 4);
    int*   ntcnt  = (int*)  alloc(NTY * 4);
    float* bn1    = (float*)alloc(2 * D * 4);
    float* bn2    = (float*)alloc(2 * D * 4);
    float* bn3    = (float*)alloc(2 * D * 4);
    float* sumsxf = (float*)alloc(NE * D * 4);
    int*   outdeg = (int*)  alloc(NN * 4);
    int*   indeg  = (int*)  alloc(NN * 4);
    size_t zero_end = off;
    // ---- rest ----
    int* tcnt = (int*)alloc(NE * 4);
    int* soff_ = (int*)alloc((NN + 1) * 4);
    int* doff_ = (int*)alloc((NN + 1) * 4);
    int* scur = (int*)alloc(NN * 4);
    int* dcur = (int*)alloc(NN * 4);
    int* slist = (int*)alloc((size_t)EE * 4);
    int* dlist = (int*)alloc((size_t)EE * 4);
    unsigned short* combo = (unsigned short*)alloc((size_t)EE * 2);
    short* Bpk  = (short*)alloc((size_t)5 * NTILES * KSTEPS * 1024 * 2);   // 5 mats, bf16 hi/lo packed
    float* h1v   = (float*)alloc((size_t)NCT * D * 4);
    float* embE  = (float*)alloc((size_t)NC * D * 4);
    float* embS  = (float*)alloc((size_t)NTY * D * 4);
    float* h2pre = (float*)alloc((size_t)NC * D * 4);
    float* Rc    = (float*)alloc((size_t)NC * D * 4);
    float* upd   = (float*)alloc((size_t)BG * D * 4);
    float* GK    = (float*)alloc((size_t)BG * D * 4);
    float* GM    = (float*)alloc((size_t)BG * D * 4);
    float* SK    = (float*)alloc((size_t)NTY * D * 4);
    float* SM    = (float*)alloc((size_t)NTY * D * 4);
    float* sc    = (float*)alloc((size_t)EA * H * 4);
    float* XK    = (float*)alloc((size_t)NN * D * 4);
    float* XM    = (float*)alloc((size_t)NN * D * 4);
    float* XQ    = (float*)alloc((size_t)NN * D * 4);
    // aliases (liveness-checked):
    float* coef  = XK;            // dead before k_mmf3 writes XK
    float* scale = h1v;           // h1v dead before k_soft writes scale
    float* aggr  = XQ;            // XQ dead after k_soft
    float* T1    = XK;            // XK dead after k_soft

    const int matstride = NTILES * KSTEPS * 1024;   // shorts per packed mat

    hipMemsetAsync(ws, 0, zero_end, stream);
    hipMemsetAsync(coef, 0, (size_t)NN * NE * 4, stream);

    k_packW  <<<5 * NTILES * KSTEPS, 256, 0, stream>>>(Wk, Wm, Wq, Wo1, Wo2, Bpk);
    k_hist   <<<EE / 256, 256, 0, stream>>>(ei, et, nt, hist, outdeg, indeg, combo);
    k_ntcnt  <<<NN / 256, 256, 0, stream>>>(nt, ntcnt);
    k_coef   <<<EE / 256, 256, 0, stream>>>(ei, et, coef);
    k_tcnt   <<<1, 64, 0, stream>>>(hist, tcnt);
    k_scan   <<<1, 256, 0, stream>>>(outdeg, indeg, soff_, doff_, scur, dcur);
    k_scatter<<<EE / 256, 256, 0, stream>>>(ei, scur, dcur, slist, dlist);
    k_xfsum3 <<<256, 256, 0, stream>>>(x, coef, sumsxf);
    k_combos1<<<NCT, 256, 0, stream>>>(We1, be1, hist, ntcnt, h1v, bn1);
    k_combos2<<<NCT, 256, 0, stream>>>(h1v, bn1, ge1, bte1, We2, be2, embE, embS);
    k_combos3<<<NC, 256, 0, stream>>>(embE, sumsxf, tcnt, Wa1, ba1, hist, h2pre, bn2);
    k_combos4<<<NC, 256, 0, stream>>>(h2pre, bn2, ga1, bta1, Wa2, ba2, Rc);
    k_attn   <<<BG, 256, 0, stream>>>(sent, Watt, Rc, combo, upd);
    k_gkgm   <<<BG + NTY, 256, 0, stream>>>(upd, embS, Wk, bk, Wm, bm, GK, GM, SK, SM);
    k_mmf3   <<<NN / 64, 256, 0, stream>>>(x, Bpk, bq, XK, XM, XQ);
    k_soft   <<<NN / 4, 256, 0, stream>>>(ei, nt, soff_, slist, outdeg, XQ, XK, GK, SK, sc, scale);
    k_aggr   <<<NN / 4, 256, 0, stream>>>(ei, nt, doff_, dlist, sc, scale, XM, GM, SM, aggr);
    k_mmf    <<<NN / 64, 256, 0, stream>>>(aggr, Bpk + (size_t)3 * matstride, bo1, T1,
                                           0, nullptr, 0.f, nullptr, nullptr, 1.f);
    k_colstats<<<NN / 256, 256, 0, stream>>>(T1, bn3);
    k_mmf    <<<NN / 64, 256, 0, stream>>>(T1, Bpk + (size_t)4 * matstride, bo2, (float*)d_out,
                                           1, bn3, 1.f / (float)NN, go1, bto1, 1.f);
}

// Round 6
// 1293.079 us; speedup vs baseline: 2.0967x; 1.0288x over previous
//
#include <hip/hip_runtime.h>

#define D     200
#define H     4
#define DH    50
#define NE    38
#define NTY   4
#define NC    608      // edge combos = 38*4*4
#define NCT   612      // + 4 self combos
#define BG    256      // graphs
#define LG    1024     // edges per graph
#define EE    262144   // E
#define NN    51200    // N
#define EA    313344   // E + N

#define NTILES 13      // ceil(200/16)
#define KSTEPS 7       // ceil(200/32)

typedef __attribute__((ext_vector_type(4))) float  f32x4;
typedef __attribute__((ext_vector_type(8))) short  bf16x8;

__device__ __forceinline__ short bf_hi(float f) {
    unsigned u = __float_as_uint(f);
    unsigned r = u + 0x7fffu + ((u >> 16) & 1u);
    return (short)(r >> 16);
}
__device__ __forceinline__ float bf_f(short s) {
    return __uint_as_float(((unsigned)(unsigned short)s) << 16);
}

// ---------------- histogram / combo / degrees / per-graph combo hist ----------------
__global__ __launch_bounds__(256) void k_hist(const int* __restrict__ ei, const int* __restrict__ et,
                                              const int* __restrict__ nt, int* hist, int* outdeg, int* indeg,
                                              int* hcnt) {
    int e = blockIdx.x * 256 + threadIdx.x;
    if (e >= EE) return;
    int s = ei[e], d = ei[EE + e];
    int c = et[e] * 16 + nt[s] * 4 + nt[d];
    atomicAdd(&hist[c], 1);
    atomicAdd(&outdeg[s], 1);
    atomicAdd(&indeg[d], 1);
    atomicAdd(&hcnt[(e >> 10) * NC + c], 1);
}

// per-block LDS reduction -> 4 global atomics per block
__global__ __launch_bounds__(256) void k_ntcnt(const int* __restrict__ nt, int* ntcnt) {
    __shared__ int loc[NTY];
    int t = threadIdx.x;
    if (t < NTY) loc[t] = 0;
    __syncthreads();
    int n = blockIdx.x * 256 + t;
    if (n < NN) atomicAdd(&loc[nt[n]], 1);
    __syncthreads();
    if (t < NTY) atomicAdd(&ntcnt[t], loc[t]);
}

__global__ void k_tcnt(const int* __restrict__ hist, int* tcnt) {
    int t = threadIdx.x;
    if (t < NE) { int s = 0; for (int i = 0; i < 16; i++) s += hist[t*16 + i]; tcnt[t] = s; }
}

// ---------------- per-(node,type) signed coefficients ----------------
__global__ __launch_bounds__(256) void k_coef(const int* __restrict__ ei, const int* __restrict__ et,
                                              float* coef) {
    int e = blockIdx.x * 256 + threadIdx.x;
    if (e >= EE) return;
    int s = ei[e], d = ei[EE + e], t = et[e];
    unsafeAtomicAdd(&coef[(size_t)d * NE + t],  1.f);
    unsafeAtomicAdd(&coef[(size_t)s * NE + t], -1.f);
}

// sums = coef^T (38 x NN) @ x (NN x 200), K-split GEMM.
__global__ __launch_bounds__(256) void k_xfsum3(const float* __restrict__ x, const float* __restrict__ coef,
                                                float* sums) {
    const int CH = NN / 256;   // 200 nodes per block
    int t = threadIdx.x;
    int n0 = blockIdx.x * CH;
    float acc[NE];
    #pragma unroll
    for (int m = 0; m < NE; m++) acc[m] = 0.f;
    if (t < D) {
        for (int k = 0; k < CH; k++) {
            int n = n0 + k;
            float xv = x[(size_t)n * D + t];
            const float* cf = coef + (size_t)n * NE;
            #pragma unroll
            for (int m = 0; m < NE; m++) acc[m] += cf[m] * xv;
        }
        #pragma unroll
        for (int m = 0; m < NE; m++)
            if (acc[m] != 0.f) unsafeAtomicAdd(&sums[m * D + t], acc[m]);
    }
}

// ---------------- CSR build: scan + scatter ----------------
__global__ __launch_bounds__(256) void k_scan(const int* __restrict__ a, const int* __restrict__ b,
                                              int* aoff, int* boff, int* acur, int* bcur) {
    __shared__ int pa[256], pb[256];
    int t = threadIdx.x;
    const int CH = NN / 256;   // 200
    int base = t * CH;
    int s0 = 0, s1 = 0;
    for (int i = 0; i < CH; i++) { s0 += a[base + i]; s1 += b[base + i]; }
    pa[t] = s0; pb[t] = s1; __syncthreads();
    for (int off = 1; off < 256; off <<= 1) {
        int va = (t >= off) ? pa[t - off] : 0;
        int vb = (t >= off) ? pb[t - off] : 0;
        __syncthreads();
        pa[t] += va; pb[t] += vb;
        __syncthreads();
    }
    int ra = pa[t] - s0, rb = pb[t] - s1;
    for (int i = 0; i < CH; i++) {
        aoff[base + i] = ra; acur[base + i] = ra; ra += a[base + i];
        boff[base + i] = rb; bcur[base + i] = rb; rb += b[base + i];
    }
    if (t == 255) { aoff[NN] = ra; boff[NN] = rb; }
}

__global__ __launch_bounds__(256) void k_scatter(const int* __restrict__ ei, int* scur, int* dcur,
                                                 int* slist, int* dlist) {
    int e = blockIdx.x * 256 + threadIdx.x;
    if (e >= EE) return;
    int s = ei[e], d = ei[EE + e];
    slist[atomicAdd(&scur[s], 1)] = e;
    dlist[atomicAdd(&dcur[d], 1)] = e;
}

// ---------------- per-combo MLP pipeline ----------------
__global__ __launch_bounds__(256) void k_combos1(const float* __restrict__ We1, const float* __restrict__ be1,
                                                 const int* __restrict__ hist, const int* __restrict__ ntcnt,
                                                 float* __restrict__ h1, float* bn1) {
    int c = blockIdx.x, d = threadIdx.x;
    if (d >= D) return;
    float v, w;
    if (c < NC) {
        int etp = c >> 4, ts = (c >> 2) & 3, td = c & 3;
        v = We1[etp*D + d] + We1[(39+ts)*D + d] + We1[(43+td)*D + d] + be1[d];
        w = (float)hist[c];
    } else {
        int t = c - NC;
        v = We1[38*D + d] + We1[(39+t)*D + d] + We1[(43+t)*D + d] + be1[d];
        w = (float)ntcnt[t];
    }
    h1[c*D + d] = v;
    unsafeAtomicAdd(&bn1[d], w * v);
    unsafeAtomicAdd(&bn1[D + d], w * v * v);
}

__global__ __launch_bounds__(256) void k_combos2(const float* __restrict__ h1, const float* __restrict__ bn1,
                                                 const float* __restrict__ ge1, const float* __restrict__ bte1,
                                                 const float* __restrict__ We2, const float* __restrict__ be2,
                                                 float* __restrict__ embE, float* __restrict__ embS) {
    __shared__ float v[D];
    int c = blockIdx.x, t = threadIdx.x;
    if (t < D) {
        float cnt = (float)(EE + NN);
        float m = bn1[t] / cnt;
        float var = bn1[D + t] / cnt - m * m;
        float r = rsqrtf(var + 1e-5f);
        float u = (h1[c*D + t] - m) * r * ge1[t] + bte1[t];
        v[t] = fmaxf(u, 0.f);
    }
    __syncthreads();
    if (t < D) {
        float acc = be2[t];
        for (int k = 0; k < D; k++) acc += v[k] * We2[k*D + t];
        if (c < NC) embE[c*D + t] = acc; else embS[(c-NC)*D + t] = acc;
    }
}

__global__ __launch_bounds__(256) void k_combos3(const float* __restrict__ embE, const float* __restrict__ sumsxf,
                                                 const int* __restrict__ tcnt, const float* __restrict__ Wa1,
                                                 const float* __restrict__ ba1, const int* __restrict__ hist,
                                                 float* __restrict__ h2, float* bn2) {
    __shared__ float a[2*D];
    int c = blockIdx.x, t = threadIdx.x;
    int etp = c >> 4;
    if (t < D) {
        a[t] = embE[c*D + t];
        float cn = fmaxf((float)tcnt[etp], 1.f);
        a[D + t] = sumsxf[etp*D + t] / cn;
    }
    __syncthreads();
    if (t < D) {
        float acc = ba1[t];
        for (int k = 0; k < 2*D; k++) acc += a[k] * Wa1[k*D + t];
        h2[c*D + t] = acc;
        float w = (float)hist[c];
        unsafeAtomicAdd(&bn2[t], w * acc);
        unsafeAtomicAdd(&bn2[D + t], w * acc * acc);
    }
}

__global__ __launch_bounds__(256) void k_combos4(const float* __restrict__ h2, const float* __restrict__ bn2,
                                                 const float* __restrict__ ga1, const float* __restrict__ bta1,
                                                 const float* __restrict__ Wa2, const float* __restrict__ ba2,
                                                 float* __restrict__ Rc) {
    __shared__ float v[D];
    int c = blockIdx.x, t = threadIdx.x;
    if (t < D) {
        float inv = 1.f / (float)EE;
        float m = bn2[t] * inv;
        float var = bn2[D + t] * inv - m * m;
        float r = rsqrtf(var + 1e-5f);
        float u = (h2[c*D + t] - m) * r * ga1[t] + bta1[t];
        v[t] = fmaxf(u, 0.f);
    }
    __syncthreads();
    if (t < D) {
        float acc = ba2[t];
        for (int k = 0; k < D; k++) acc += v[k] * Wa2[k*D + t];
        Rc[c*D + t] = acc;
    }
}

// ---------------- per-graph attention, collapsed to combo space ----------------
// scores depend only on combo (608 rows), so softmax over 1024 edges ==
// weighted softmax over 608 combos with per-graph counts hcnt.
__global__ __launch_bounds__(256) void k_attn(const float* __restrict__ sent, const float* __restrict__ Watt,
                                              const float* __restrict__ Rc, const int* __restrict__ hcnt,
                                              float* __restrict__ upd) {
    __shared__ float q[D];
    __shared__ float w[NC];
    __shared__ float red[8];
    int b = blockIdx.x, t = threadIdx.x;
    int wave = t >> 6, lane = t & 63;
    if (t < D) {
        float acc = 0.f;
        for (int k = 0; k < D; k++) acc += sent[b*D + k] * Watt[k*D + t];
        q[t] = acc;
    }
    __syncthreads();
    const float scl = 0.07071067811865475f;   // 1/sqrt(200)
    for (int c = wave; c < NC; c += 4) {
        const float* r = Rc + c * D;
        float p = 0.f;
        for (int dd = lane; dd < D; dd += 64) p += q[dd] * r[dd];
        for (int o = 32; o; o >>= 1) p += __shfl_xor(p, o);
        if (lane == 0) w[c] = p * scl;
    }
    __syncthreads();
    // max over ALL combos: softmax is shift-invariant, absent combos contribute 0 to denom
    float mx = -1e30f;
    for (int c = t; c < NC; c += 256) mx = fmaxf(mx, w[c]);
    for (int o = 32; o; o >>= 1) mx = fmaxf(mx, __shfl_xor(mx, o));
    if (lane == 0) red[wave] = mx;
    __syncthreads();
    mx = fmaxf(fmaxf(red[0], red[1]), fmaxf(red[2], red[3]));
    float sm = 0.f;
    for (int c = t; c < NC; c += 256) {
        float wv = (float)hcnt[b * NC + c] * __expf(w[c] - mx);
        w[c] = wv;
        sm += wv;
    }
    for (int o = 32; o; o >>= 1) sm += __shfl_xor(sm, o);
    if (lane == 0) red[4 + wave] = sm;
    __syncthreads();
    float inv = 1.f / (red[4] + red[5] + red[6] + red[7]);
    if (t < D) {
        float acc = 0.f;
        for (int c = 0; c < NC; c++) acc += w[c] * Rc[c * D + t];
        upd[b * D + t] = acc * inv;
    }
}

// ---------------- GK/GM (per graph) and SK/SM (per node type) ----------------
__global__ __launch_bounds__(256) void k_gkgm(const float* __restrict__ upd, const float* __restrict__ embS,
                                              const float* __restrict__ Wk, const float* __restrict__ bk,
                                              const float* __restrict__ Wm, const float* __restrict__ bm,
                                              float* GK, float* GM, float* SK, float* SM) {
    __shared__ float v[D];
    int bI = blockIdx.x, t = threadIdx.x;
    const float* in = (bI < BG) ? (upd + bI*D) : (embS + (bI - BG)*D);
    if (t < D) v[t] = in[t];
    __syncthreads();
    if (t < D) {
        float a1 = bk[t], a2 = bm[t];
        for (int k = 0; k < D; k++) {
            a1 += v[k] * Wk[(D + k)*D + t];
            a2 += v[k] * Wm[(D + k)*D + t];
        }
        if (bI < BG) { GK[bI*D + t] = a1; GM[bI*D + t] = a2; }
        else         { SK[(bI-BG)*D + t] = a1; SM[(bI-BG)*D + t] = a2; }
    }
}

// ---------------- weight packing: B-fragment order, bf16 hi/lo ----------------
__global__ __launch_bounds__(256) void k_packW(const float* __restrict__ Wk, const float* __restrict__ Wm,
                                               const float* __restrict__ Wq, const float* __restrict__ Wo1,
                                               const float* __restrict__ Wo2, short* __restrict__ Bpk) {
    int blk = blockIdx.x;                    // mat*91 + nt*7 + ks
    int mat = blk / (NTILES * KSTEPS);
    int rem = blk - mat * (NTILES * KSTEPS);
    int nt = rem / KSTEPS, ks = rem - nt * KSTEPS;
    const float* W = (mat == 0) ? Wk : (mat == 1) ? Wm : (mat == 2) ? Wq : (mat == 3) ? Wo1 : Wo2;
    int t = threadIdx.x;
    for (int idx = t; idx < 1024; idx += 256) {
        int split = idx >> 9;
        int lane = (idx & 511) >> 3;
        int j = idx & 7;
        int n = nt * 16 + (lane & 15);
        int k = ks * 32 + ((lane >> 4) << 3) + j;
        float v = (k < D && n < D) ? W[k * D + n] : 0.f;
        short h = bf_hi(v);
        short out = split ? bf_hi(v - bf_f(h)) : h;
        Bpk[(size_t)blk * 1024 + idx] = out;
    }
}

// ---------------- MFMA GEMM core helpers ----------------
__device__ __forceinline__ void stage_A(const float* __restrict__ A, int n0, short* Apk,
                                        int preop, const float* scl, const float* sft) {
    int t = threadIdx.x;
    bf16x8* Apk8 = (bf16x8*)Apk;
    for (int f = t; f < 64 * 28; f += 256) {
        int r = f / 28, g = f - 28 * r;
        float v[8];
        if (g < 25) {
            const float* src = A + (size_t)(n0 + r) * D + g * 8;
            float4 p0 = *(const float4*)src;
            float4 p1 = *(const float4*)(src + 4);
            v[0]=p0.x; v[1]=p0.y; v[2]=p0.z; v[3]=p0.w;
            v[4]=p1.x; v[5]=p1.y; v[6]=p1.z; v[7]=p1.w;
            if (preop) {
                #pragma unroll
                for (int j = 0; j < 8; j++) v[j] = fmaxf(v[j] * scl[g*8+j] + sft[g*8+j], 0.f);
            }
        } else {
            #pragma unroll
            for (int j = 0; j < 8; j++) v[j] = 0.f;
        }
        bf16x8 hi, lo;
        #pragma unroll
        for (int j = 0; j < 8; j++) {
            short h = bf_hi(v[j]);
            hi[j] = h;
            lo[j] = bf_hi(v[j] - bf_f(h));
        }
        int strip = r >> 4, lanem = r & 15, ks = g >> 2, quad = g & 3;
        int lane = lanem | (quad << 4);
        Apk8[((strip * KSTEPS + ks) * 2 + 0) * 64 + lane] = hi;
        Apk8[((strip * KSTEPS + ks) * 2 + 1) * 64 + lane] = lo;
    }
}

__device__ __forceinline__ void mfma_strip(const short* Apk, const short* Bmat, int w, int lane,
                                           f32x4 acc[NTILES]) {
    const bf16x8* Apk8 = (const bf16x8*)Apk;
    const bf16x8* B8   = (const bf16x8*)Bmat;
    #pragma unroll
    for (int nt = 0; nt < NTILES; nt++) { acc[nt][0]=0.f; acc[nt][1]=0.f; acc[nt][2]=0.f; acc[nt][3]=0.f; }
    for (int ks = 0; ks < KSTEPS; ks++) {
        bf16x8 ah = Apk8[((w * KSTEPS + ks) * 2 + 0) * 64 + lane];
        bf16x8 al = Apk8[((w * KSTEPS + ks) * 2 + 1) * 64 + lane];
        #pragma unroll
        for (int nt = 0; nt < NTILES; nt++) {
            bf16x8 bh = B8[((nt * KSTEPS + ks) * 2 + 0) * 64 + lane];
            bf16x8 bl = B8[((nt * KSTEPS + ks) * 2 + 1) * 64 + lane];
            acc[nt] = __builtin_amdgcn_mfma_f32_16x16x32_bf16(al, bh, acc[nt], 0, 0, 0);
            acc[nt] = __builtin_amdgcn_mfma_f32_16x16x32_bf16(ah, bl, acc[nt], 0, 0, 0);
            acc[nt] = __builtin_amdgcn_mfma_f32_16x16x32_bf16(ah, bh, acc[nt], 0, 0, 0);
        }
    }
}

__device__ __forceinline__ void store_C(f32x4 acc[NTILES], float* __restrict__ C, int n0, int w, int lane,
                                        const float* __restrict__ bias, float postscale) {
    int colb = lane & 15, quad = lane >> 4;
    #pragma unroll
    for (int nt = 0; nt < NTILES; nt++) {
        int col = nt * 16 + colb;
        if (col < D) {
            float bj = bias ? bias[col] : 0.f;
            #pragma unroll
            for (int r = 0; r < 4; r++) {
                int row = n0 + w * 16 + quad * 4 + r;
                C[(size_t)row * D + col] = (acc[nt][r] + bj) * postscale;
            }
        }
    }
}

// ---------------- fused x @ {Wk[:D], Wm[:D], Wq}  (MFMA) ----------------
__global__ __launch_bounds__(256) void k_mmf3(const float* __restrict__ A, const short* __restrict__ Bpk,
                                              const float* __restrict__ bq,
                                              float* __restrict__ XK, float* __restrict__ XM, float* __restrict__ XQ) {
    __shared__ short Apk[4 * KSTEPS * 2 * 64 * 8];
    int n0 = blockIdx.x * 64;
    stage_A(A, n0, Apk, 0, nullptr, nullptr);
    __syncthreads();
    int w = threadIdx.x >> 6, lane = threadIdx.x & 63;
    f32x4 acc[NTILES];
    const int matstride = NTILES * KSTEPS * 1024;   // shorts per mat = 91*1024
    mfma_strip(Apk, Bpk + 0 * matstride, w, lane, acc);
    store_C(acc, XK, n0, w, lane, nullptr, 1.f);
    mfma_strip(Apk, Bpk + 1 * matstride, w, lane, acc);
    store_C(acc, XM, n0, w, lane, nullptr, 1.f);
    mfma_strip(Apk, Bpk + 2 * matstride, w, lane, acc);
    store_C(acc, XQ, n0, w, lane, bq, 0.14142135623730950488f);
}

// ---------------- generic MFMA matmul (one B), optional BN+relu preop ----------------
__global__ __launch_bounds__(256) void k_mmf(const float* __restrict__ A, const short* __restrict__ Bmat,
                                             const float* __restrict__ bias, float* __restrict__ C,
                                             int preop, const float* __restrict__ bnacc, float invCnt,
                                             const float* __restrict__ g, const float* __restrict__ bb,
                                             float postscale) {
    __shared__ short Apk[4 * KSTEPS * 2 * 64 * 8];
    __shared__ float scl[D], sft[D];
    int t = threadIdx.x;
    int n0 = blockIdx.x * 64;
    if (preop) {
        if (t < D) {
            float m = bnacc[t] * invCnt;
            float var = bnacc[D + t] * invCnt - m * m;
            float rs = rsqrtf(var + 1e-5f);
            float s = rs * g[t];
            scl[t] = s;
            sft[t] = bb[t] - m * s;
        }
        __syncthreads();
    }
    stage_A(A, n0, Apk, preop, scl, sft);
    __syncthreads();
    int w = t >> 6, lane = t & 63;
    f32x4 acc[NTILES];
    mfma_strip(Apk, Bmat, w, lane, acc);
    store_C(acc, C, n0, w, lane, bias, postscale);
}

// ---------------- edge softmax, src-CSR, wave per node, no atomics ----------------
__global__ __launch_bounds__(256) void k_soft(const int* __restrict__ ei, const int* __restrict__ nt,
                                              const int* __restrict__ soff, const int* __restrict__ slist,
                                              const int* __restrict__ outdeg,
                                              const float* __restrict__ XQ, const float* __restrict__ XK,
                                              const float* __restrict__ GK, const float* __restrict__ SK,
                                              float* __restrict__ sc, float* __restrict__ scale) {
    int wave = threadIdx.x >> 6, lane = threadIdx.x & 63;
    int n = blockIdx.x * 4 + wave;
    if (n >= NN) return;
    float qv[4];
    #pragma unroll
    for (int j = 0; j < 4; j++) { int dd = lane + 64*j; qv[j] = (dd < D) ? XQ[(size_t)n*D + dd] : 0.f; }
    float den0 = 0.f, den1 = 0.f, den2 = 0.f, den3 = 0.f;
    {
        int tn = nt[n];
        float h0 = 0, h1 = 0, h2 = 0, h3 = 0;
        #pragma unroll
        for (int j = 0; j < 4; j++) {
            int dd = lane + 64*j;
            if (dd < D) {
                float p = qv[j] * (XK[(size_t)n*D + dd] + SK[tn*D + dd]);
                int hh = dd / DH;
                if (hh == 0) h0 += p; else if (hh == 1) h1 += p; else if (hh == 2) h2 += p; else h3 += p;
            }
        }
        for (int o = 32; o; o >>= 1) {
            h0 += __shfl_xor(h0, o); h1 += __shfl_xor(h1, o);
            h2 += __shfl_xor(h2, o); h3 += __shfl_xor(h3, o);
        }
        float e0 = __expf(h0), e1 = __expf(h1), e2 = __expf(h2), e3 = __expf(h3);
        den0 += e0; den1 += e1; den2 += e2; den3 += e3;
        if (lane < 4) {
            float v = (lane == 0) ? e0 : (lane == 1) ? e1 : (lane == 2) ? e2 : e3;
            sc[(size_t)(EE + n) * 4 + lane] = v;
        }
    }
    int beg = soff[n], end = soff[n + 1];
    for (int i = beg; i < end; i++) {
        int e = slist[i];
        int tail = ei[EE + e];
        int g = e >> 10;
        float h0 = 0, h1 = 0, h2 = 0, h3 = 0;
        #pragma unroll
        for (int j = 0; j < 4; j++) {
            int dd = lane + 64*j;
            if (dd < D) {
                float p = qv[j] * (XK[(size_t)tail*D + dd] + GK[g*D + dd]);
                int hh = dd / DH;
                if (hh == 0) h0 += p; else if (hh == 1) h1 += p; else if (hh == 2) h2 += p; else h3 += p;
            }
        }
        for (int o = 32; o; o >>= 1) {
            h0 += __shfl_xor(h0, o); h1 += __shfl_xor(h1, o);
            h2 += __shfl_xor(h2, o); h3 += __shfl_xor(h3, o);
        }
        float e0 = __expf(h0), e1 = __expf(h1), e2 = __expf(h2), e3 = __expf(h3);
        den0 += e0; den1 += e1; den2 += e2; den3 += e3;
        if (lane < 4) {
            float v = (lane == 0) ? e0 : (lane == 1) ? e1 : (lane == 2) ? e2 : e3;
            sc[(size_t)e * 4 + lane] = v;
        }
    }
    float cnt = (float)(outdeg[n] + 1);
    if (lane < 4) {
        float dn = (lane == 0) ? den0 : (lane == 1) ? den1 : (lane == 2) ? den2 : den3;
        scale[(size_t)n * 4 + lane] = cnt / dn;
    }
}

// ---------------- aggregation, dst-CSR, wave per node, no atomics ----------------
__global__ __launch_bounds__(256) void k_aggr(const int* __restrict__ ei, const int* __restrict__ nt,
                                              const int* __restrict__ doff, const int* __restrict__ dlist,
                                              const float* __restrict__ sc, const float* __restrict__ scale,
                                              const float* __restrict__ XM, const float* __restrict__ GM,
                                              const float* __restrict__ SM, float* __restrict__ aggr) {
    int wave = threadIdx.x >> 6, lane = threadIdx.x & 63;
    int n = blockIdx.x * 4 + wave;
    if (n >= NN) return;
    float acc[4] = {0.f, 0.f, 0.f, 0.f};
    {
        int tn = nt[n];
        float4 ss = *(const float4*)&sc[(size_t)(EE + n) * 4];
        float4 sl = *(const float4*)&scale[(size_t)n * 4];
        float a0 = ss.x * sl.x, a1 = ss.y * sl.y, a2 = ss.z * sl.z, a3 = ss.w * sl.w;
        #pragma unroll
        for (int j = 0; j < 4; j++) {
            int dd = lane + 64*j;
            if (dd < D) {
                float al = (dd < DH) ? a0 : (dd < 2*DH) ? a1 : (dd < 3*DH) ? a2 : a3;
                acc[j] += al * (XM[(size_t)n*D + dd] + SM[tn*D + dd]);
            }
        }
    }
    int beg = doff[n], end = doff[n + 1];
    for (int i = beg; i < end; i++) {
        int e = dlist[i];
        int s = ei[e];
        int g = e >> 10;
        float4 ss = *(const float4*)&sc[(size_t)e * 4];
        float4 sl = *(const float4*)&scale[(size_t)s * 4];
        float a0 = ss.x * sl.x, a1 = ss.y * sl.y, a2 = ss.z * sl.z, a3 = ss.w * sl.w;
        #pragma unroll
        for (int j = 0; j < 4; j++) {
            int dd = lane + 64*j;
            if (dd < D) {
                float al = (dd < DH) ? a0 : (dd < 2*DH) ? a1 : (dd < 3*DH) ? a2 : a3;
                acc[j] += al * (XM[(size_t)s*D + dd] + GM[g*D + dd]);
            }
        }
    }
    #pragma unroll
    for (int j = 0; j < 4; j++) {
        int dd = lane + 64*j;
        if (dd < D) aggr[(size_t)n*D + dd] = acc[j];
    }
}

// ---------------- column stats for final BN ----------------
__global__ __launch_bounds__(256) void k_colstats(const float* __restrict__ T1, float* bn3) {
    int t = threadIdx.x;
    if (t >= D) return;
    int r0 = blockIdx.x * 256;
    float s = 0.f, q = 0.f;
    for (int r = r0; r < r0 + 256; r++) {
        float v = T1[(size_t)r * D + t];
        s += v; q += v * v;
    }
    unsafeAtomicAdd(&bn3[t], s);
    unsafeAtomicAdd(&bn3[D + t], q);
}

extern "C" void kernel_launch(void* const* d_in, const int* in_sizes, int n_in,
                              void* d_out, int out_size, void* d_ws, size_t ws_size,
                              hipStream_t stream) {
    const float* x    = (const float*)d_in[0];
    const float* sent = (const float*)d_in[2];
    const float* We1  = (const float*)d_in[3];
    const float* be1  = (const float*)d_in[4];
    const float* ge1  = (const float*)d_in[5];
    const float* bte1 = (const float*)d_in[6];
    const float* We2  = (const float*)d_in[7];
    const float* be2  = (const float*)d_in[8];
    const float* Wa1  = (const float*)d_in[9];
    const float* ba1  = (const float*)d_in[10];
    const float* ga1  = (const float*)d_in[11];
    const float* bta1 = (const float*)d_in[12];
    const float* Wa2  = (const float*)d_in[13];
    const float* ba2  = (const float*)d_in[14];
    const float* Watt = (const float*)d_in[15];
    const float* Wk   = (const float*)d_in[16];
    const float* bk   = (const float*)d_in[17];
    const float* Wm   = (const float*)d_in[18];
    const float* bm   = (const float*)d_in[19];
    const float* Wq   = (const float*)d_in[20];
    const float* bq   = (const float*)d_in[21];
    const float* Wo1  = (const float*)d_in[22];
    const float* bo1  = (const float*)d_in[23];
    const float* go1  = (const float*)d_in[24];
    const float* bto1 = (const float*)d_in[25];
    const float* Wo2  = (const float*)d_in[26];
    const float* bo2  = (const float*)d_in[27];
    const int* ei = (const int*)d_in[28];
    const int* et = (const int*)d_in[29];
    const int* nt = (const int*)d_in[30];

    char* ws = (char*)d_ws;
    size_t off = 0;
    auto alloc = [&](size_t bytes) -> char* {
        char* p = ws + off;
        off = (off + bytes + 255) & ~(size_t)255;
        return p;
    };
    // ---- zeroed region ----
    int*   hist   = (int*)  alloc(NC * 4);
    int*   ntcnt  = (int*)  alloc(NTY * 4);
    float* bn1    = (float*)alloc(2 * D * 4);
    float* bn2    = (float*)alloc(2 * D * 4);
    float* bn3    = (float*)alloc(2 * D * 4);
    float* sumsxf = (float*)alloc(NE * D * 4);
    int*   outdeg = (int*)  alloc(NN * 4);
    int*   indeg  = (int*)  alloc(NN * 4);
    int*   hcnt   = (int*)  alloc((size_t)BG * NC * 4);   // per-graph combo histogram
    size_t zero_end = off;
    // ---- rest ----
    int* tcnt = (int*)alloc(NE * 4);
    int* soff_ = (int*)alloc((NN + 1) * 4);
    int* doff_ = (int*)alloc((NN + 1) * 4);
    int* scur = (int*)alloc(NN * 4);
    int* dcur = (int*)alloc(NN * 4);
    int* slist = (int*)alloc((size_t)EE * 4);
    int* dlist = (int*)alloc((size_t)EE * 4);
    short* Bpk  = (short*)alloc((size_t)5 * NTILES * KSTEPS * 1024 * 2);   // 5 mats, bf16 hi/lo packed
    float* h1v   = (float*)alloc((size_t)NCT * D * 4);
    float* embE  = (float*)alloc((size_t)NC * D * 4);
    float* embS  = (float*)alloc((size_t)NTY * D * 4);
    float* h2pre = (float*)alloc((size_t)NC * D * 4);
    float* Rc    = (float*)alloc((size_t)NC * D * 4);
    float* upd   = (float*)alloc((size_t)BG * D * 4);
    float* GK    = (float*)alloc((size_t)BG * D * 4);
    float* GM    = (float*)alloc((size_t)BG * D * 4);
    float* SK    = (float*)alloc((size_t)NTY * D * 4);
    float* SM    = (float*)alloc((size_t)NTY * D * 4);
    float* sc    = (float*)alloc((size_t)EA * H * 4);
    float* XK    = (float*)alloc((size_t)NN * D * 4);
    float* XM    = (float*)alloc((size_t)NN * D * 4);
    float* XQ    = (float*)alloc((size_t)NN * D * 4);
    // aliases (liveness-checked):
    float* coef  = XK;            // dead before k_mmf3 writes XK
    float* scale = h1v;           // h1v dead before k_soft writes scale
    float* aggr  = XQ;            // XQ dead after k_soft
    float* T1    = XK;            // XK dead after k_soft

    const int matstride = NTILES * KSTEPS * 1024;   // shorts per packed mat

    hipMemsetAsync(ws, 0, zero_end, stream);
    hipMemsetAsync(coef, 0, (size_t)NN * NE * 4, stream);

    k_packW  <<<5 * NTILES * KSTEPS, 256, 0, stream>>>(Wk, Wm, Wq, Wo1, Wo2, Bpk);
    k_hist   <<<EE / 256, 256, 0, stream>>>(ei, et, nt, hist, outdeg, indeg, hcnt);
    k_ntcnt  <<<NN / 256, 256, 0, stream>>>(nt, ntcnt);
    k_coef   <<<EE / 256, 256, 0, stream>>>(ei, et, coef);
    k_tcnt   <<<1, 64, 0, stream>>>(hist, tcnt);
    k_scan   <<<1, 256, 0, stream>>>(outdeg, indeg, soff_, doff_, scur, dcur);
    k_scatter<<<EE / 256, 256, 0, stream>>>(ei, scur, dcur, slist, dlist);
    k_xfsum3 <<<256, 256, 0, stream>>>(x, coef, sumsxf);
    k_combos1<<<NCT, 256, 0, stream>>>(We1, be1, hist, ntcnt, h1v, bn1);
    k_combos2<<<NCT, 256, 0, stream>>>(h1v, bn1, ge1, bte1, We2, be2, embE, embS);
    k_combos3<<<NC, 256, 0, stream>>>(embE, sumsxf, tcnt, Wa1, ba1, hist, h2pre, bn2);
    k_combos4<<<NC, 256, 0, stream>>>(h2pre, bn2, ga1, bta1, Wa2, ba2, Rc);
    k_attn   <<<BG, 256, 0, stream>>>(sent, Watt, Rc, hcnt, upd);
    k_gkgm   <<<BG + NTY, 256, 0, stream>>>(upd, embS, Wk, bk, Wm, bm, GK, GM, SK, SM);
    k_mmf3   <<<NN / 64, 256, 0, stream>>>(x, Bpk, bq, XK, XM, XQ);
    k_soft   <<<NN / 4, 256, 0, stream>>>(ei, nt, soff_, slist, outdeg, XQ, XK, GK, SK, sc, scale);
    k_aggr   <<<NN / 4, 256, 0, stream>>>(ei, nt, doff_, dlist, sc, scale, XM, GM, SM, aggr);
    k_mmf    <<<NN / 64, 256, 0, stream>>>(aggr, Bpk + (size_t)3 * matstride, bo1, T1,
                                           0, nullptr, 0.f, nullptr, nullptr, 1.f);
    k_colstats<<<NN / 256, 256, 0, stream>>>(T1, bn3);
    k_mmf    <<<NN / 64, 256, 0, stream>>>(T1, Bpk + (size_t)4 * matstride, bo2, (float*)d_out,
                                           1, bn3, 1.f / (float)NN, go1, bto1, 1.f);
}

// Round 7
// 1242.488 us; speedup vs baseline: 2.1820x; 1.0407x over previous
//
#include <hip/hip_runtime.h>

#define D     200
#define H     4
#define DH    50
#define NE    38
#define NTY   4
#define NC    608      // edge combos = 38*4*4
#define NCT   612      // + 4 self combos
#define BG    256      // graphs
#define LG    1024     // edges per graph
#define EE    262144   // E
#define NN    51200    // N
#define EA    313344   // E + N

#define NTILES 13      // ceil(200/16)
#define KSTEPS 7       // ceil(200/32)

typedef __attribute__((ext_vector_type(4))) float  f32x4;
typedef __attribute__((ext_vector_type(8))) short  bf16x8;

__device__ __forceinline__ short bf_hi(float f) {
    unsigned u = __float_as_uint(f);
    unsigned r = u + 0x7fffu + ((u >> 16) & 1u);
    return (short)(r >> 16);
}
__device__ __forceinline__ float bf_f(short s) {
    return __uint_as_float(((unsigned)(unsigned short)s) << 16);
}

// ---------------- histogram / combo / degrees / per-graph combo hist ----------------
__global__ __launch_bounds__(256) void k_hist(const int* __restrict__ ei, const int* __restrict__ et,
                                              const int* __restrict__ nt, int* hist, int* outdeg, int* indeg,
                                              int* hcnt) {
    int e = blockIdx.x * 256 + threadIdx.x;
    if (e >= EE) return;
    int s = ei[e], d = ei[EE + e];
    int c = et[e] * 16 + nt[s] * 4 + nt[d];
    atomicAdd(&hist[c], 1);
    atomicAdd(&outdeg[s], 1);
    atomicAdd(&indeg[d], 1);
    atomicAdd(&hcnt[(e >> 10) * NC + c], 1);
}

// per-block LDS reduction -> 4 global atomics per block
__global__ __launch_bounds__(256) void k_ntcnt(const int* __restrict__ nt, int* ntcnt) {
    __shared__ int loc[NTY];
    int t = threadIdx.x;
    if (t < NTY) loc[t] = 0;
    __syncthreads();
    int n = blockIdx.x * 256 + t;
    if (n < NN) atomicAdd(&loc[nt[n]], 1);
    __syncthreads();
    if (t < NTY) atomicAdd(&ntcnt[t], loc[t]);
}

__global__ void k_tcnt(const int* __restrict__ hist, int* tcnt) {
    int t = threadIdx.x;
    if (t < NE) { int s = 0; for (int i = 0; i < 16; i++) s += hist[t*16 + i]; tcnt[t] = s; }
}

// ---------------- per-(node,type) signed coefficients ----------------
__global__ __launch_bounds__(256) void k_coef(const int* __restrict__ ei, const int* __restrict__ et,
                                              float* coef) {
    int e = blockIdx.x * 256 + threadIdx.x;
    if (e >= EE) return;
    int s = ei[e], d = ei[EE + e], t = et[e];
    unsafeAtomicAdd(&coef[(size_t)d * NE + t],  1.f);
    unsafeAtomicAdd(&coef[(size_t)s * NE + t], -1.f);
}

// sums = coef^T (38 x NN) @ x (NN x 200), K-split GEMM.
__global__ __launch_bounds__(256) void k_xfsum3(const float* __restrict__ x, const float* __restrict__ coef,
                                                float* sums) {
    const int CH = NN / 256;   // 200 nodes per block
    int t = threadIdx.x;
    int n0 = blockIdx.x * CH;
    float acc[NE];
    #pragma unroll
    for (int m = 0; m < NE; m++) acc[m] = 0.f;
    if (t < D) {
        for (int k = 0; k < CH; k++) {
            int n = n0 + k;
            float xv = x[(size_t)n * D + t];
            const float* cf = coef + (size_t)n * NE;
            #pragma unroll
            for (int m = 0; m < NE; m++) acc[m] += cf[m] * xv;
        }
        #pragma unroll
        for (int m = 0; m < NE; m++)
            if (acc[m] != 0.f) unsafeAtomicAdd(&sums[m * D + t], acc[m]);
    }
}

// ---------------- CSR build: scan + scatter ----------------
__global__ __launch_bounds__(256) void k_scan(const int* __restrict__ a, const int* __restrict__ b,
                                              int* aoff, int* boff, int* acur, int* bcur) {
    __shared__ int pa[256], pb[256];
    int t = threadIdx.x;
    const int CH = NN / 256;   // 200
    int base = t * CH;
    int s0 = 0, s1 = 0;
    for (int i = 0; i < CH; i++) { s0 += a[base + i]; s1 += b[base + i]; }
    pa[t] = s0; pb[t] = s1; __syncthreads();
    for (int off = 1; off < 256; off <<= 1) {
        int va = (t >= off) ? pa[t - off] : 0;
        int vb = (t >= off) ? pb[t - off] : 0;
        __syncthreads();
        pa[t] += va; pb[t] += vb;
        __syncthreads();
    }
    int ra = pa[t] - s0, rb = pb[t] - s1;
    for (int i = 0; i < CH; i++) {
        aoff[base + i] = ra; acur[base + i] = ra; ra += a[base + i];
        boff[base + i] = rb; bcur[base + i] = rb; rb += b[base + i];
    }
    if (t == 255) { aoff[NN] = ra; boff[NN] = rb; }
}

__global__ __launch_bounds__(256) void k_scatter(const int* __restrict__ ei, int* scur, int* dcur,
                                                 int* slist, int* dlist) {
    int e = blockIdx.x * 256 + threadIdx.x;
    if (e >= EE) return;
    int s = ei[e], d = ei[EE + e];
    slist[atomicAdd(&scur[s], 1)] = e;
    dlist[atomicAdd(&dcur[d], 1)] = e;
}

// ---------------- per-combo MLP pipeline ----------------
__global__ __launch_bounds__(256) void k_combos1(const float* __restrict__ We1, const float* __restrict__ be1,
                                                 const int* __restrict__ hist, const int* __restrict__ ntcnt,
                                                 float* __restrict__ h1, float* bn1) {
    int c = blockIdx.x, d = threadIdx.x;
    if (d >= D) return;
    float v, w;
    if (c < NC) {
        int etp = c >> 4, ts = (c >> 2) & 3, td = c & 3;
        v = We1[etp*D + d] + We1[(39+ts)*D + d] + We1[(43+td)*D + d] + be1[d];
        w = (float)hist[c];
    } else {
        int t = c - NC;
        v = We1[38*D + d] + We1[(39+t)*D + d] + We1[(43+t)*D + d] + be1[d];
        w = (float)ntcnt[t];
    }
    h1[c*D + d] = v;
    unsafeAtomicAdd(&bn1[d], w * v);
    unsafeAtomicAdd(&bn1[D + d], w * v * v);
}

__global__ __launch_bounds__(256) void k_combos2(const float* __restrict__ h1, const float* __restrict__ bn1,
                                                 const float* __restrict__ ge1, const float* __restrict__ bte1,
                                                 const float* __restrict__ We2, const float* __restrict__ be2,
                                                 float* __restrict__ embE, float* __restrict__ embS) {
    __shared__ float v[D];
    int c = blockIdx.x, t = threadIdx.x;
    if (t < D) {
        float cnt = (float)(EE + NN);
        float m = bn1[t] / cnt;
        float var = bn1[D + t] / cnt - m * m;
        float r = rsqrtf(var + 1e-5f);
        float u = (h1[c*D + t] - m) * r * ge1[t] + bte1[t];
        v[t] = fmaxf(u, 0.f);
    }
    __syncthreads();
    if (t < D) {
        float acc = be2[t];
        for (int k = 0; k < D; k++) acc += v[k] * We2[k*D + t];
        if (c < NC) embE[c*D + t] = acc; else embS[(c-NC)*D + t] = acc;
    }
}

__global__ __launch_bounds__(256) void k_combos3(const float* __restrict__ embE, const float* __restrict__ sumsxf,
                                                 const int* __restrict__ tcnt, const float* __restrict__ Wa1,
                                                 const float* __restrict__ ba1, const int* __restrict__ hist,
                                                 float* __restrict__ h2, float* bn2) {
    __shared__ float a[2*D];
    int c = blockIdx.x, t = threadIdx.x;
    int etp = c >> 4;
    if (t < D) {
        a[t] = embE[c*D + t];
        float cn = fmaxf((float)tcnt[etp], 1.f);
        a[D + t] = sumsxf[etp*D + t] / cn;
    }
    __syncthreads();
    if (t < D) {
        float acc = ba1[t];
        for (int k = 0; k < 2*D; k++) acc += a[k] * Wa1[k*D + t];
        h2[c*D + t] = acc;
        float w = (float)hist[c];
        unsafeAtomicAdd(&bn2[t], w * acc);
        unsafeAtomicAdd(&bn2[D + t], w * acc * acc);
    }
}

// also writes RcT (200 x 608) for the coalesced attention score pass
__global__ __launch_bounds__(256) void k_combos4(const float* __restrict__ h2, const float* __restrict__ bn2,
                                                 const float* __restrict__ ga1, const float* __restrict__ bta1,
                                                 const float* __restrict__ Wa2, const float* __restrict__ ba2,
                                                 float* __restrict__ Rc, float* __restrict__ RcT) {
    __shared__ float v[D];
    int c = blockIdx.x, t = threadIdx.x;
    if (t < D) {
        float inv = 1.f / (float)EE;
        float m = bn2[t] * inv;
        float var = bn2[D + t] * inv - m * m;
        float r = rsqrtf(var + 1e-5f);
        float u = (h2[c*D + t] - m) * r * ga1[t] + bta1[t];
        v[t] = fmaxf(u, 0.f);
    }
    __syncthreads();
    if (t < D) {
        float acc = ba2[t];
        for (int k = 0; k < D; k++) acc += v[k] * Wa2[k*D + t];
        Rc[c*D + t] = acc;
        RcT[(size_t)t * NC + c] = acc;
    }
}

// ---------------- per-graph attention, combo space, MLP-friendly layout ----------------
__global__ __launch_bounds__(256) void k_attn(const float* __restrict__ sent, const float* __restrict__ Watt,
                                              const float* __restrict__ Rc, const float* __restrict__ RcT,
                                              const int* __restrict__ hcnt, float* __restrict__ upd) {
    __shared__ float q[D];
    __shared__ float w[NC];
    __shared__ float red[8];
    __shared__ float part[4][D];
    int b = blockIdx.x, t = threadIdx.x;
    int wave = t >> 6, lane = t & 63;
    // q = sent[b] @ Watt
    if (t < D) {
        float acc = 0.f;
        for (int k = 0; k < D; k++) acc += sent[b*D + k] * Watt[k*D + t];
        q[t] = acc;
    }
    __syncthreads();
    // scores: thread t owns combos {t, t+256, t+512}; RcT rows -> coalesced, pipelined
    const float scl = 0.07071067811865475f;   // 1/sqrt(200)
    {
        float s0 = 0.f, s1 = 0.f, s2 = 0.f;
        for (int k = 0; k < D; k++) {
            float qk = q[k];
            const float* row = RcT + (size_t)k * NC;
            s0 += qk * row[t];
            s1 += qk * row[t + 256];
            if (t < NC - 512) s2 += qk * row[t + 512];
        }
        w[t] = s0 * scl;
        w[t + 256] = s1 * scl;
        if (t < NC - 512) w[t + 512] = s2 * scl;
    }
    __syncthreads();
    // max over all combos (shift-invariant; absent combos weighted 0 in denom)
    float mx = -1e30f;
    for (int c = t; c < NC; c += 256) mx = fmaxf(mx, w[c]);
    for (int o = 32; o; o >>= 1) mx = fmaxf(mx, __shfl_xor(mx, o));
    if (lane == 0) red[wave] = mx;
    __syncthreads();
    mx = fmaxf(fmaxf(red[0], red[1]), fmaxf(red[2], red[3]));
    float sm = 0.f;
    for (int c = t; c < NC; c += 256) {
        float wv = (float)hcnt[b * NC + c] * __expf(w[c] - mx);
        w[c] = wv;
        sm += wv;
    }
    for (int o = 32; o; o >>= 1) sm += __shfl_xor(sm, o);
    if (lane == 0) red[4 + wave] = sm;
    __syncthreads();
    float inv = 1.f / (red[4] + red[5] + red[6] + red[7]);
    // upd: wave partials over 152 combos each, coalesced Rc reads, LDS reduce
    float a4[4] = {0.f, 0.f, 0.f, 0.f};
    for (int c = wave * (NC/4); c < (wave + 1) * (NC/4); c++) {
        float wv = w[c];
        const float* r = Rc + c * D;
        #pragma unroll
        for (int j = 0; j < 4; j++) { int dd = lane + 64*j; if (dd < D) a4[j] += wv * r[dd]; }
    }
    #pragma unroll
    for (int j = 0; j < 4; j++) { int dd = lane + 64*j; if (dd < D) part[wave][dd] = a4[j]; }
    __syncthreads();
    if (t < D) upd[b*D + t] = (part[0][t] + part[1][t] + part[2][t] + part[3][t]) * inv;
}

// ---------------- GK/GM (per graph) and SK/SM (per node type) ----------------
__global__ __launch_bounds__(256) void k_gkgm(const float* __restrict__ upd, const float* __restrict__ embS,
                                              const float* __restrict__ Wk, const float* __restrict__ bk,
                                              const float* __restrict__ Wm, const float* __restrict__ bm,
                                              float* GK, float* GM, float* SK, float* SM) {
    __shared__ float v[D];
    int bI = blockIdx.x, t = threadIdx.x;
    const float* in = (bI < BG) ? (upd + bI*D) : (embS + (bI - BG)*D);
    if (t < D) v[t] = in[t];
    __syncthreads();
    if (t < D) {
        float a1 = bk[t], a2 = bm[t];
        for (int k = 0; k < D; k++) {
            a1 += v[k] * Wk[(D + k)*D + t];
            a2 += v[k] * Wm[(D + k)*D + t];
        }
        if (bI < BG) { GK[bI*D + t] = a1; GM[bI*D + t] = a2; }
        else         { SK[(bI-BG)*D + t] = a1; SM[(bI-BG)*D + t] = a2; }
    }
}

// ---------------- weight packing: B-fragment order, bf16 hi/lo ----------------
__global__ __launch_bounds__(256) void k_packW(const float* __restrict__ Wk, const float* __restrict__ Wm,
                                               const float* __restrict__ Wq, const float* __restrict__ Wo1,
                                               const float* __restrict__ Wo2, short* __restrict__ Bpk) {
    int blk = blockIdx.x;                    // mat*91 + nt*7 + ks
    int mat = blk / (NTILES * KSTEPS);
    int rem = blk - mat * (NTILES * KSTEPS);
    int nt = rem / KSTEPS, ks = rem - nt * KSTEPS;
    const float* W = (mat == 0) ? Wk : (mat == 1) ? Wm : (mat == 2) ? Wq : (mat == 3) ? Wo1 : Wo2;
    int t = threadIdx.x;
    for (int idx = t; idx < 1024; idx += 256) {
        int split = idx >> 9;
        int lane = (idx & 511) >> 3;
        int j = idx & 7;
        int n = nt * 16 + (lane & 15);
        int k = ks * 32 + ((lane >> 4) << 3) + j;
        float v = (k < D && n < D) ? W[k * D + n] : 0.f;
        short h = bf_hi(v);
        short out = split ? bf_hi(v - bf_f(h)) : h;
        Bpk[(size_t)blk * 1024 + idx] = out;
    }
}

// ---------------- MFMA GEMM core helpers ----------------
__device__ __forceinline__ void stage_A(const float* __restrict__ A, int n0, short* Apk,
                                        int preop, const float* scl, const float* sft) {
    int t = threadIdx.x;
    bf16x8* Apk8 = (bf16x8*)Apk;
    for (int f = t; f < 64 * 28; f += 256) {
        int r = f / 28, g = f - 28 * r;
        float v[8];
        if (g < 25) {
            const float* src = A + (size_t)(n0 + r) * D + g * 8;
            float4 p0 = *(const float4*)src;
            float4 p1 = *(const float4*)(src + 4);
            v[0]=p0.x; v[1]=p0.y; v[2]=p0.z; v[3]=p0.w;
            v[4]=p1.x; v[5]=p1.y; v[6]=p1.z; v[7]=p1.w;
            if (preop) {
                #pragma unroll
                for (int j = 0; j < 8; j++) v[j] = fmaxf(v[j] * scl[g*8+j] + sft[g*8+j], 0.f);
            }
        } else {
            #pragma unroll
            for (int j = 0; j < 8; j++) v[j] = 0.f;
        }
        bf16x8 hi, lo;
        #pragma unroll
        for (int j = 0; j < 8; j++) {
            short h = bf_hi(v[j]);
            hi[j] = h;
            lo[j] = bf_hi(v[j] - bf_f(h));
        }
        int strip = r >> 4, lanem = r & 15, ks = g >> 2, quad = g & 3;
        int lane = lanem | (quad << 4);
        Apk8[((strip * KSTEPS + ks) * 2 + 0) * 64 + lane] = hi;
        Apk8[((strip * KSTEPS + ks) * 2 + 1) * 64 + lane] = lo;
    }
}

__device__ __forceinline__ void mfma_strip(const short* Apk, const short* Bmat, int w, int lane,
                                           f32x4 acc[NTILES]) {
    const bf16x8* Apk8 = (const bf16x8*)Apk;
    const bf16x8* B8   = (const bf16x8*)Bmat;
    #pragma unroll
    for (int nt = 0; nt < NTILES; nt++) { acc[nt][0]=0.f; acc[nt][1]=0.f; acc[nt][2]=0.f; acc[nt][3]=0.f; }
    for (int ks = 0; ks < KSTEPS; ks++) {
        bf16x8 ah = Apk8[((w * KSTEPS + ks) * 2 + 0) * 64 + lane];
        bf16x8 al = Apk8[((w * KSTEPS + ks) * 2 + 1) * 64 + lane];
        #pragma unroll
        for (int nt = 0; nt < NTILES; nt++) {
            bf16x8 bh = B8[((nt * KSTEPS + ks) * 2 + 0) * 64 + lane];
            bf16x8 bl = B8[((nt * KSTEPS + ks) * 2 + 1) * 64 + lane];
            acc[nt] = __builtin_amdgcn_mfma_f32_16x16x32_bf16(al, bh, acc[nt], 0, 0, 0);
            acc[nt] = __builtin_amdgcn_mfma_f32_16x16x32_bf16(ah, bl, acc[nt], 0, 0, 0);
            acc[nt] = __builtin_amdgcn_mfma_f32_16x16x32_bf16(ah, bh, acc[nt], 0, 0, 0);
        }
    }
}

__device__ __forceinline__ void store_C(f32x4 acc[NTILES], float* __restrict__ C, int n0, int w, int lane,
                                        const float* __restrict__ bias, float postscale) {
    int colb = lane & 15, quad = lane >> 4;
    #pragma unroll
    for (int nt = 0; nt < NTILES; nt++) {
        int col = nt * 16 + colb;
        if (col < D) {
            float bj = bias ? bias[col] : 0.f;
            #pragma unroll
            for (int r = 0; r < 4; r++) {
                int row = n0 + w * 16 + quad * 4 + r;
                C[(size_t)row * D + col] = (acc[nt][r] + bj) * postscale;
            }
        }
    }
}

// ---------------- fused x @ {Wk[:D], Wm[:D], Wq}  (MFMA) ----------------
__global__ __launch_bounds__(256) void k_mmf3(const float* __restrict__ A, const short* __restrict__ Bpk,
                                              const float* __restrict__ bq,
                                              float* __restrict__ XK, float* __restrict__ XM, float* __restrict__ XQ) {
    __shared__ short Apk[4 * KSTEPS * 2 * 64 * 8];
    int n0 = blockIdx.x * 64;
    stage_A(A, n0, Apk, 0, nullptr, nullptr);
    __syncthreads();
    int w = threadIdx.x >> 6, lane = threadIdx.x & 63;
    f32x4 acc[NTILES];
    const int matstride = NTILES * KSTEPS * 1024;   // shorts per mat = 91*1024
    mfma_strip(Apk, Bpk + 0 * matstride, w, lane, acc);
    store_C(acc, XK, n0, w, lane, nullptr, 1.f);
    mfma_strip(Apk, Bpk + 1 * matstride, w, lane, acc);
    store_C(acc, XM, n0, w, lane, nullptr, 1.f);
    mfma_strip(Apk, Bpk + 2 * matstride, w, lane, acc);
    store_C(acc, XQ, n0, w, lane, bq, 0.14142135623730950488f);
}

// ---------------- generic MFMA matmul (one B), optional BN+relu preop ----------------
__global__ __launch_bounds__(256) void k_mmf(const float* __restrict__ A, const short* __restrict__ Bmat,
                                             const float* __restrict__ bias, float* __restrict__ C,
                                             int preop, const float* __restrict__ bnacc, float invCnt,
                                             const float* __restrict__ g, const float* __restrict__ bb,
                                             float postscale) {
    __shared__ short Apk[4 * KSTEPS * 2 * 64 * 8];
    __shared__ float scl[D], sft[D];
    int t = threadIdx.x;
    int n0 = blockIdx.x * 64;
    if (preop) {
        if (t < D) {
            float m = bnacc[t] * invCnt;
            float var = bnacc[D + t] * invCnt - m * m;
            float rs = rsqrtf(var + 1e-5f);
            float s = rs * g[t];
            scl[t] = s;
            sft[t] = bb[t] - m * s;
        }
        __syncthreads();
    }
    stage_A(A, n0, Apk, preop, scl, sft);
    __syncthreads();
    int w = t >> 6, lane = t & 63;
    f32x4 acc[NTILES];
    mfma_strip(Apk, Bmat, w, lane, acc);
    store_C(acc, C, n0, w, lane, bias, postscale);
}

// ---------------- edge softmax, src-CSR, wave per node, no atomics ----------------
__global__ __launch_bounds__(256) void k_soft(const int* __restrict__ ei, const int* __restrict__ nt,
                                              const int* __restrict__ soff, const int* __restrict__ slist,
                                              const int* __restrict__ outdeg,
                                              const float* __restrict__ XQ, const float* __restrict__ XK,
                                              const float* __restrict__ GK, const float* __restrict__ SK,
                                              float* __restrict__ sc, float* __restrict__ scale) {
    int wave = threadIdx.x >> 6, lane = threadIdx.x & 63;
    int n = blockIdx.x * 4 + wave;
    if (n >= NN) return;
    float qv[4];
    #pragma unroll
    for (int j = 0; j < 4; j++) { int dd = lane + 64*j; qv[j] = (dd < D) ? XQ[(size_t)n*D + dd] : 0.f; }
    float den0 = 0.f, den1 = 0.f, den2 = 0.f, den3 = 0.f;
    {
        int tn = nt[n];
        float h0 = 0, h1 = 0, h2 = 0, h3 = 0;
        #pragma unroll
        for (int j = 0; j < 4; j++) {
            int dd = lane + 64*j;
            if (dd < D) {
                float p = qv[j] * (XK[(size_t)n*D + dd] + SK[tn*D + dd]);
                int hh = dd / DH;
                if (hh == 0) h0 += p; else if (hh == 1) h1 += p; else if (hh == 2) h2 += p; else h3 += p;
            }
        }
        for (int o = 32; o; o >>= 1) {
            h0 += __shfl_xor(h0, o); h1 += __shfl_xor(h1, o);
            h2 += __shfl_xor(h2, o); h3 += __shfl_xor(h3, o);
        }
        float e0 = __expf(h0), e1 = __expf(h1), e2 = __expf(h2), e3 = __expf(h3);
        den0 += e0; den1 += e1; den2 += e2; den3 += e3;
        if (lane < 4) {
            float v = (lane == 0) ? e0 : (lane == 1) ? e1 : (lane == 2) ? e2 : e3;
            sc[(size_t)(EE + n) * 4 + lane] = v;
        }
    }
    int beg = soff[n], end = soff[n + 1];
    for (int i = beg; i < end; i++) {
        int e = slist[i];
        int tail = ei[EE + e];
        int g = e >> 10;
        float h0 = 0, h1 = 0, h2 = 0, h3 = 0;
        #pragma unroll
        for (int j = 0; j < 4; j++) {
            int dd = lane + 64*j;
            if (dd < D) {
                float p = qv[j] * (XK[(size_t)tail*D + dd] + GK[g*D + dd]);
                int hh = dd / DH;
                if (hh == 0) h0 += p; else if (hh == 1) h1 += p; else if (hh == 2) h2 += p; else h3 += p;
            }
        }
        for (int o = 32; o; o >>= 1) {
            h0 += __shfl_xor(h0, o); h1 += __shfl_xor(h1, o);
            h2 += __shfl_xor(h2, o); h3 += __shfl_xor(h3, o);
        }
        float e0 = __expf(h0), e1 = __expf(h1), e2 = __expf(h2), e3 = __expf(h3);
        den0 += e0; den1 += e1; den2 += e2; den3 += e3;
        if (lane < 4) {
            float v = (lane == 0) ? e0 : (lane == 1) ? e1 : (lane == 2) ? e2 : e3;
            sc[(size_t)e * 4 + lane] = v;
        }
    }
    float cnt = (float)(outdeg[n] + 1);
    if (lane < 4) {
        float dn = (lane == 0) ? den0 : (lane == 1) ? den1 : (lane == 2) ? den2 : den3;
        scale[(size_t)n * 4 + lane] = cnt / dn;
    }
}

// ---------------- aggregation, dst-CSR, wave per node, no atomics ----------------
__global__ __launch_bounds__(256) void k_aggr(const int* __restrict__ ei, const int* __restrict__ nt,
                                              const int* __restrict__ doff, const int* __restrict__ dlist,
                                              const float* __restrict__ sc, const float* __restrict__ scale,
                                              const float* __restrict__ XM, const float* __restrict__ GM,
                                              const float* __restrict__ SM, float* __restrict__ aggr) {
    int wave = threadIdx.x >> 6, lane = threadIdx.x & 63;
    int n = blockIdx.x * 4 + wave;
    if (n >= NN) return;
    float acc[4] = {0.f, 0.f, 0.f, 0.f};
    {
        int tn = nt[n];
        float4 ss = *(const float4*)&sc[(size_t)(EE + n) * 4];
        float4 sl = *(const float4*)&scale[(size_t)n * 4];
        float a0 = ss.x * sl.x, a1 = ss.y * sl.y, a2 = ss.z * sl.z, a3 = ss.w * sl.w;
        #pragma unroll
        for (int j = 0; j < 4; j++) {
            int dd = lane + 64*j;
            if (dd < D) {
                float al = (dd < DH) ? a0 : (dd < 2*DH) ? a1 : (dd < 3*DH) ? a2 : a3;
                acc[j] += al * (XM[(size_t)n*D + dd] + SM[tn*D + dd]);
            }
        }
    }
    int beg = doff[n], end = doff[n + 1];
    for (int i = beg; i < end; i++) {
        int e = dlist[i];
        int s = ei[e];
        int g = e >> 10;
        float4 ss = *(const float4*)&sc[(size_t)e * 4];
        float4 sl = *(const float4*)&scale[(size_t)s * 4];
        float a0 = ss.x * sl.x, a1 = ss.y * sl.y, a2 = ss.z * sl.z, a3 = ss.w * sl.w;
        #pragma unroll
        for (int j = 0; j < 4; j++) {
            int dd = lane + 64*j;
            if (dd < D) {
                float al = (dd < DH) ? a0 : (dd < 2*DH) ? a1 : (dd < 3*DH) ? a2 : a3;
                acc[j] += al * (XM[(size_t)s*D + dd] + GM[g*D + dd]);
            }
        }
    }
    #pragma unroll
    for (int j = 0; j < 4; j++) {
        int dd = lane + 64*j;
        if (dd < D) aggr[(size_t)n*D + dd] = acc[j];
    }
}

// ---------------- column stats for final BN ----------------
__global__ __launch_bounds__(256) void k_colstats(const float* __restrict__ T1, float* bn3) {
    int t = threadIdx.x;
    if (t >= D) return;
    int r0 = blockIdx.x * 256;
    float s = 0.f, q = 0.f;
    for (int r = r0; r < r0 + 256; r++) {
        float v = T1[(size_t)r * D + t];
        s += v; q += v * v;
    }
    unsafeAtomicAdd(&bn3[t], s);
    unsafeAtomicAdd(&bn3[D + t], q);
}

extern "C" void kernel_launch(void* const* d_in, const int* in_sizes, int n_in,
                              void* d_out, int out_size, void* d_ws, size_t ws_size,
                              hipStream_t stream) {
    const float* x    = (const float*)d_in[0];
    const float* sent = (const float*)d_in[2];
    const float* We1  = (const float*)d_in[3];
    const float* be1  = (const float*)d_in[4];
    const float* ge1  = (const float*)d_in[5];
    const float* bte1 = (const float*)d_in[6];
    const float* We2  = (const float*)d_in[7];
    const float* be2  = (const float*)d_in[8];
    const float* Wa1  = (const float*)d_in[9];
    const float* ba1  = (const float*)d_in[10];
    const float* ga1  = (const float*)d_in[11];
    const float* bta1 = (const float*)d_in[12];
    const float* Wa2  = (const float*)d_in[13];
    const float* ba2  = (const float*)d_in[14];
    const float* Watt = (const float*)d_in[15];
    const float* Wk   = (const float*)d_in[16];
    const float* bk   = (const float*)d_in[17];
    const float* Wm   = (const float*)d_in[18];
    const float* bm   = (const float*)d_in[19];
    const float* Wq   = (const float*)d_in[20];
    const float* bq   = (const float*)d_in[21];
    const float* Wo1  = (const float*)d_in[22];
    const float* bo1  = (const float*)d_in[23];
    const float* go1  = (const float*)d_in[24];
    const float* bto1 = (const float*)d_in[25];
    const float* Wo2  = (const float*)d_in[26];
    const float* bo2  = (const float*)d_in[27];
    const int* ei = (const int*)d_in[28];
    const int* et = (const int*)d_in[29];
    const int* nt = (const int*)d_in[30];

    char* ws = (char*)d_ws;
    size_t off = 0;
    auto alloc = [&](size_t bytes) -> char* {
        char* p = ws + off;
        off = (off + bytes + 255) & ~(size_t)255;
        return p;
    };
    // ---- zeroed region ----
    int*   hist   = (int*)  alloc(NC * 4);
    int*   ntcnt  = (int*)  alloc(NTY * 4);
    float* bn1    = (float*)alloc(2 * D * 4);
    float* bn2    = (float*)alloc(2 * D * 4);
    float* bn3    = (float*)alloc(2 * D * 4);
    float* sumsxf = (float*)alloc(NE * D * 4);
    int*   outdeg = (int*)  alloc(NN * 4);
    int*   indeg  = (int*)  alloc(NN * 4);
    int*   hcnt   = (int*)  alloc((size_t)BG * NC * 4);   // per-graph combo histogram
    size_t zero_end = off;
    // ---- rest ----
    int* tcnt = (int*)alloc(NE * 4);
    int* soff_ = (int*)alloc((NN + 1) * 4);
    int* doff_ = (int*)alloc((NN + 1) * 4);
    int* scur = (int*)alloc(NN * 4);
    int* dcur = (int*)alloc(NN * 4);
    int* slist = (int*)alloc((size_t)EE * 4);
    int* dlist = (int*)alloc((size_t)EE * 4);
    short* Bpk  = (short*)alloc((size_t)5 * NTILES * KSTEPS * 1024 * 2);   // 5 mats, bf16 hi/lo packed
    float* h1v   = (float*)alloc((size_t)NCT * D * 4);
    float* embE  = (float*)alloc((size_t)NC * D * 4);
    float* embS  = (float*)alloc((size_t)NTY * D * 4);
    float* h2pre = (float*)alloc((size_t)NC * D * 4);
    float* Rc    = (float*)alloc((size_t)NC * D * 4);
    float* RcT   = (float*)alloc((size_t)D * NC * 4);
    float* upd   = (float*)alloc((size_t)BG * D * 4);
    float* GK    = (float*)alloc((size_t)BG * D * 4);
    float* GM    = (float*)alloc((size_t)BG * D * 4);
    float* SK    = (float*)alloc((size_t)NTY * D * 4);
    float* SM    = (float*)alloc((size_t)NTY * D * 4);
    float* sc    = (float*)alloc((size_t)EA * H * 4);
    float* XK    = (float*)alloc((size_t)NN * D * 4);
    float* XM    = (float*)alloc((size_t)NN * D * 4);
    float* XQ    = (float*)alloc((size_t)NN * D * 4);
    // aliases (liveness-checked):
    float* coef  = XK;            // dead before k_mmf3 writes XK
    float* scale = h1v;           // h1v dead before k_soft writes scale
    float* aggr  = XQ;            // XQ dead after k_soft
    float* T1    = XK;            // XK dead after k_soft

    const int matstride = NTILES * KSTEPS * 1024;   // shorts per packed mat

    hipMemsetAsync(ws, 0, zero_end, stream);
    hipMemsetAsync(coef, 0, (size_t)NN * NE * 4, stream);

    k_packW  <<<5 * NTILES * KSTEPS, 256, 0, stream>>>(Wk, Wm, Wq, Wo1, Wo2, Bpk);
    k_hist   <<<EE / 256, 256, 0, stream>>>(ei, et, nt, hist, outdeg, indeg, hcnt);
    k_ntcnt  <<<NN / 256, 256, 0, stream>>>(nt, ntcnt);
    k_coef   <<<EE / 256, 256, 0, stream>>>(ei, et, coef);
    k_tcnt   <<<1, 64, 0, stream>>>(hist, tcnt);
    k_scan   <<<1, 256, 0, stream>>>(outdeg, indeg, soff_, doff_, scur, dcur);
    k_scatter<<<EE / 256, 256, 0, stream>>>(ei, scur, dcur, slist, dlist);
    k_xfsum3 <<<256, 256, 0, stream>>>(x, coef, sumsxf);
    k_combos1<<<NCT, 256, 0, stream>>>(We1, be1, hist, ntcnt, h1v, bn1);
    k_combos2<<<NCT, 256, 0, stream>>>(h1v, bn1, ge1, bte1, We2, be2, embE, embS);
    k_combos3<<<NC, 256, 0, stream>>>(embE, sumsxf, tcnt, Wa1, ba1, hist, h2pre, bn2);
    k_combos4<<<NC, 256, 0, stream>>>(h2pre, bn2, ga1, bta1, Wa2, ba2, Rc, RcT);
    k_attn   <<<BG, 256, 0, stream>>>(sent, Watt, Rc, RcT, hcnt, upd);
    k_gkgm   <<<BG + NTY, 256, 0, stream>>>(upd, embS, Wk, bk, Wm, bm, GK, GM, SK, SM);
    k_mmf3   <<<NN / 64, 256, 0, stream>>>(x, Bpk, bq, XK, XM, XQ);
    k_soft   <<<NN / 4, 256, 0, stream>>>(ei, nt, soff_, slist, outdeg, XQ, XK, GK, SK, sc, scale);
    k_aggr   <<<NN / 4, 256, 0, stream>>>(ei, nt, doff_, dlist, sc, scale, XM, GM, SM, aggr);
    k_mmf    <<<NN / 64, 256, 0, stream>>>(aggr, Bpk + (size_t)3 * matstride, bo1, T1,
                                           0, nullptr, 0.f, nullptr, nullptr, 1.f);
    k_colstats<<<NN / 256, 256, 0, stream>>>(T1, bn3);
    k_mmf    <<<NN / 64, 256, 0, stream>>>(T1, Bpk + (size_t)4 * matstride, bo2, (float*)d_out,
                                           1, bn3, 1.f / (float)NN, go1, bto1, 1.f);
}